// Round 7
// baseline (612.467 us; speedup 1.0000x reference)
//
#include <hip/hip_runtime.h>
#include <hip/hip_fp16.h>

#define N_NODES 100000
#define N_EDGES 1600000
#define SCAN_B ((N_NODES + 1023) / 1024)
#define BSHIFT 7
#define NB_BKT ((N_NODES + 127) / 128)   // 782
#define BCAP 2560                        // mean 2048, +11 sigma

typedef _Float16 half2_t __attribute__((ext_vector_type(2)));
typedef _Float16 half8_t __attribute__((ext_vector_type(8)));
typedef float f32x4 __attribute__((ext_vector_type(4)));

__device__ __forceinline__ float lrelu(float x) { return x >= 0.f ? x : 0.01f * x; }

// ---------------- dense CSR build (fallback when ws is small) ----------------
__global__ void k_count(const int* __restrict__ tgt, int* __restrict__ deg) {
    int i = blockIdx.x * 256 + threadIdx.x;
    atomicAdd(&deg[tgt[i]], 1);
}

__global__ void k_scan1(const int* __restrict__ deg, int* __restrict__ bsum) {
    __shared__ int s[256];
    int t = threadIdx.x;
    int gi = blockIdx.x * 1024 + t * 4;
    int v = 0;
    if (gi < N_NODES) {
        int4 d = *(const int4*)&deg[gi];
        v = d.x + d.y + d.z + d.w;
    }
    s[t] = v;
    __syncthreads();
    for (int d = 128; d > 0; d >>= 1) {
        if (t < d) s[t] += s[t + d];
        __syncthreads();
    }
    if (t == 0) bsum[blockIdx.x] = s[0];
}

__global__ void k_scan2(int* bsum, int* rowptr) {
    if (threadIdx.x == 0) {
        int run = 0;
        for (int b = 0; b < SCAN_B; b++) {
            int v = bsum[b];
            bsum[b] = run;
            run += v;
        }
        rowptr[N_NODES] = run;
    }
}

__global__ void k_scan3(const int* __restrict__ deg, const int* __restrict__ bsum,
                        int* __restrict__ rowptr, int* __restrict__ fill) {
    __shared__ int s[256];
    int t = threadIdx.x;
    int gi = blockIdx.x * 1024 + t * 4;
    int4 d = make_int4(0, 0, 0, 0);
    if (gi < N_NODES) d = *(const int4*)&deg[gi];
    int tsum = d.x + d.y + d.z + d.w;
    s[t] = tsum;
    __syncthreads();
    for (int dd = 1; dd < 256; dd <<= 1) {
        int val = (t >= dd) ? s[t - dd] : 0;
        __syncthreads();
        s[t] += val;
        __syncthreads();
    }
    int texcl = s[t] - tsum + bsum[blockIdx.x];
    if (gi < N_NODES) {
        int4 w;
        w.x = texcl;
        w.y = texcl + d.x;
        w.z = texcl + d.x + d.y;
        w.w = texcl + d.x + d.y + d.z;
        *(int4*)&rowptr[gi] = w;
        *(int4*)&fill[gi] = w;
    }
}

__global__ void k_scatter(const int* __restrict__ src, const int* __restrict__ tgt,
                          const float2* __restrict__ ea,
                          int* __restrict__ fill, int2* __restrict__ csr) {
    int i = blockIdx.x * 256 + threadIdx.x;
    int t = tgt[i];
    float2 e = ea[i];
    int pos = atomicAdd(&fill[t], 1);
    __half2 h2 = __floats2half2_rn(e.x, e.y);
    csr[pos] = make_int2(src[i], *(int*)&h2);
}

// ---------------- two-level binning (bucket path) ----------------
__global__ __launch_bounds__(256) void k_bin1(const int* __restrict__ src,
                                              const int* __restrict__ tgt,
                                              const float2* __restrict__ ea,
                                              int* __restrict__ gCur,
                                              int2* __restrict__ bin) {
    __shared__ int hist[NB_BKT];
    __shared__ int cur[NB_BKT];
    int tid = threadIdx.x;
    for (int b = tid; b < NB_BKT; b += 256) hist[b] = 0;
    __syncthreads();
    int base = blockIdx.x * 6400;
#pragma unroll 5
    for (int k = 0; k < 25; k++) {
        int i = base + k * 256 + tid;
        atomicAdd(&hist[tgt[i] >> BSHIFT], 1);
    }
    __syncthreads();
    for (int b = tid; b < NB_BKT; b += 256)
        cur[b] = atomicAdd(&gCur[b], hist[b]);
    __syncthreads();
    for (int k = 0; k < 25; k++) {
        int i = base + k * 256 + tid;
        int t = tgt[i];
        int b = t >> BSHIFT;
        float2 e = ea[i];
        int pos = atomicAdd(&cur[b], 1);
        if (pos < BCAP) {
            __half2 h2 = __floats2half2_rn(e.x, e.y);
            int2 rec;
            rec.x = src[i] | ((t & 127) << 20);
            rec.y = *(int*)&h2;
            bin[(size_t)b * BCAP + pos] = rec;
        }
    }
}

__global__ __launch_bounds__(256) void k_bin2(const int* __restrict__ gCnt,
                                              const int2* __restrict__ bin,
                                              int2* __restrict__ csr,
                                              int* __restrict__ fill) {
    __shared__ int cnt[128];
    int tid = threadIdx.x;
    if (tid < 128) cnt[tid] = 0;
    __syncthreads();
    int b = blockIdx.x;
    int nb = min(gCnt[b], BCAP);
    const int2* myb = &bin[(size_t)b * BCAP];
    for (int i = tid; i < nb; i += 256) {
        int2 rec = myb[i];
        int tloc = (rec.x >> 20) & 127;
        int s = rec.x & 0xFFFFF;
        int pos = atomicAdd(&cnt[tloc], 1);
        if (pos < 64) {
            int node = (b << BSHIFT) + tloc;
            csr[((size_t)node << 6) + pos] = make_int2(s | (rec.x & 0xFFF00000), rec.y);
        }
    }
    __syncthreads();
    if (tid < 128) {
        int node = (b << BSHIFT) + tid;
        if (node < N_NODES) fill[node] = min(cnt[tid], 64);
    }
}

// ---------------- weight precompute ----------------
// Wcomb[64 k][144 c]: c 0-63 qmod (=0.125*Wq2 Wk2^T), 64-127 Ws2, 128 beta (u2),
// 129-130 qe (G), 131-143 zero.
__global__ void k_prep2(const float* __restrict__ Wq, const float* __restrict__ Wk,
                        const float* __restrict__ Ws, const float* __restrict__ We,
                        const float* __restrict__ bk, float* __restrict__ Wcomb) {
    int idx = blockIdx.x * 256 + threadIdx.x;  // 0..9215
    if (idx >= 9216) return;
    int j = idx / 144;
    int m = idx - j * 144;
    float v = 0.f;
    if (m < 64) {
        float s = 0.f;
        for (int ch = 0; ch < 64; ch++) s += Wq[j * 64 + ch] * Wk[m * 64 + ch];
        v = 0.125f * s;
    } else if (m < 128) {
        v = Ws[j * 64 + (m - 64)];
    } else if (m == 128) {
        float s = 0.f;
        for (int ch = 0; ch < 64; ch++) s += Wq[j * 64 + ch] * bk[ch];
        v = 0.125f * s;
    } else if (m <= 130) {
        float s = 0.f;
        for (int ch = 0; ch < 64; ch++) s += Wq[j * 64 + ch] * We[(m - 129) * 64 + ch];
        v = 0.125f * s;
    }
    Wcomb[idx] = v;
}

// bcomb[0..143]: biases for the 144 output channels; bcomb[144..159]: layer-1 consts
__global__ void k_prepb(const float* __restrict__ Wk2, const float* __restrict__ We2,
                        const float* __restrict__ bq2, const float* __restrict__ bk2,
                        const float* __restrict__ bs2, const float* __restrict__ Wq1,
                        const float* __restrict__ Wk1, const float* __restrict__ We1,
                        const float* __restrict__ bq1, const float* __restrict__ bk1,
                        float* __restrict__ bcomb) {
    int t = threadIdx.x;
    if (t >= 160) return;
    float v = 0.f;
    if (t < 64) {
        float s = 0.f;
        for (int i = 0; i < 64; i++) s += Wk2[t * 64 + i] * bq2[i];
        v = 0.125f * s;
    } else if (t < 128) {
        v = bs2[t - 64];
    } else if (t == 128) {
        float s = 0.f;
        for (int i = 0; i < 64; i++) s += bq2[i] * bk2[i];
        v = 0.125f * s;
    } else if (t <= 130) {
        float s = 0.f;
        for (int i = 0; i < 64; i++) s += bq2[i] * We2[(t - 129) * 64 + i];
        v = 0.125f * s;
    } else if (t < 144) {
        v = 0.f;
    } else {
        int t2 = t - 144;
        float s = 0.f;
        if (t2 < 4) {            // A1[j][m], j=t2>>1, m=t2&1
            int j = t2 >> 1, m = t2 & 1;
            for (int ch = 0; ch < 64; ch++) s += Wq1[j * 64 + ch] * Wk1[m * 64 + ch];
        } else if (t2 < 6) {     // u1[j]
            int j = t2 - 4;
            for (int ch = 0; ch < 64; ch++) s += Wq1[j * 64 + ch] * bk1[ch];
        } else if (t2 < 8) {     // w1[m]
            int m = t2 - 6;
            for (int ch = 0; ch < 64; ch++) s += bq1[ch] * Wk1[m * 64 + ch];
        } else if (t2 == 8) {    // c1
            for (int ch = 0; ch < 64; ch++) s += bq1[ch] * bk1[ch];
        } else if (t2 < 13) {    // B1[j][d]
            int j = (t2 - 9) >> 1, d = (t2 - 9) & 1;
            for (int ch = 0; ch < 64; ch++) s += Wq1[j * 64 + ch] * We1[d * 64 + ch];
        } else if (t2 < 15) {    // d1[d]
            int d = t2 - 13;
            for (int ch = 0; ch < 64; ch++) s += bq1[ch] * We1[d * 64 + ch];
        }
        v = 0.125f * s;
    }
    bcomb[t] = v;
}

// pack Wcomb into MFMA A-fragments: 9 M-frags x 2 kh x 64 lanes x 8 elems
__global__ void k_prepw(const float* __restrict__ Wcomb, __half* __restrict__ wp) {
    int t = blockIdx.x * 256 + threadIdx.x;  // 0..9215
    if (t >= 9216) return;
    int e = t & 7;
    int lane = (t >> 3) & 63;
    int kh = (t >> 9) & 1;
    int fm = t >> 10;  // 0..8
    int k = (kh << 5) + ((lane >> 4) << 3) + e;
    int c = fm * 16 + (lane & 15);
    wp[t] = __float2half(Wcomb[k * 144 + c]);
}

// pack Wv2 into MFMA A-fragments: 4 M-frags x 2 kh x 64 lanes x 8 elems
__global__ void k_prepv(const float* __restrict__ Wv, __half* __restrict__ wvp) {
    int t = blockIdx.x * 256 + threadIdx.x;  // 0..4095
    if (t >= 4096) return;
    int e = t & 7;
    int lane = (t >> 3) & 63;
    int kh = (t >> 9) & 1;
    int fm = t >> 10;  // 0..3
    int k = (kh << 5) + ((lane >> 4) << 3) + e;
    int c = fm * 16 + (lane & 15);
    wvp[t] = __float2half(Wv[k * 64 + c]);
}

// ---------------- layer 1 aggregation (2-dim trick): wave per node, lane per slot --
__global__ __launch_bounds__(256) void k_agg1(
    const float* __restrict__ x, const int* __restrict__ idx,
    const int2* __restrict__ csr, const float* __restrict__ Wv,
    const float* __restrict__ We, const float* __restrict__ Ws,
    const float* __restrict__ bv, const float* __restrict__ bs,
    const float* __restrict__ prep, __half* __restrict__ oh, int bucket) {
    int node = blockIdx.x * 4 + (threadIdx.x >> 6);
    int lane = threadIdx.x & 63;
    float2 xt = *(const float2*)&x[(size_t)node << 1];
    float a0 = xt.x * prep[0] + xt.y * prep[2] + prep[6];
    float a1 = xt.x * prep[1] + xt.y * prep[3] + prep[7];
    float b1 = xt.x * prep[4] + xt.y * prep[5] + prep[8];
    float g0 = xt.x * prep[9] + xt.y * prep[11] + prep[13];
    float g1 = xt.x * prep[10] + xt.y * prep[12] + prep[14];

    float l = 0.f, px0 = 0.f, px1 = 0.f, pA = 0.f, pB = 0.f;
    if (bucket) {
        int deg = idx[node];
        bool valid = lane < deg;
        int2 rec = valid ? csr[((size_t)node << 6) + lane] : make_int2(0, 0);
        int src = rec.x & 0xFFFFF;
        float2 ef = __half22float2(*(__half2*)&rec.y);
        float2 xs = valid ? *(const float2*)&x[(size_t)src << 1] : make_float2(0.f, 0.f);
        float t = a0 * xs.x + a1 * xs.y + b1 + g0 * ef.x + g1 * ef.y;
        float pp = valid ? __expf(t) : 0.f;
        l = pp;
        px0 = pp * xs.x;
        px1 = pp * xs.y;
        pA = pp * ef.x;
        pB = pp * ef.y;
    } else {
        int beg = idx[node], end = idx[node + 1];
        for (int p = beg + lane; p < end; p += 64) {
            int2 rec = csr[p];
            float2 ef = __half22float2(*(__half2*)&rec.y);
            float2 xs = *(const float2*)&x[(size_t)rec.x << 1];
            float t = a0 * xs.x + a1 * xs.y + b1 + g0 * ef.x + g1 * ef.y;
            float pp = __expf(t);
            l += pp;
            px0 += pp * xs.x;
            px1 += pp * xs.y;
            pA += pp * ef.x;
            pB += pp * ef.y;
        }
    }
#pragma unroll
    for (int D = 1; D < 64; D <<= 1) {
        l += __shfl_xor(l, D, 64);
        px0 += __shfl_xor(px0, D, 64);
        px1 += __shfl_xor(px1, D, 64);
        pA += __shfl_xor(pA, D, 64);
        pB += __shfl_xor(pB, D, 64);
    }
    float inv = 1.f / (l + 1e-16f);
    int c = lane;
    float r = (px0 * Wv[c] + px1 * Wv[64 + c] + pA * We[c] + pB * We[64 + c] +
               l * bv[c]) * inv +
              xt.x * Ws[c] + xt.y * Ws[64 + c] + bs[c];
    oh[((size_t)node << 6) + c] = __float2half(r);
}

// ---------------- batch norm ----------------
__global__ void k_bnp(const __half* __restrict__ oh, float* __restrict__ bnsum,
                      float* __restrict__ bnsq) {
    __shared__ float s1[256], s2[256];
    int t = threadIdx.x;
    int c = t & 63, nsub = t >> 6;
    float su = 0.f, sq = 0.f;
    int base = blockIdx.x * 400;
    for (int i = 0; i < 100; i++) {
        int node = base + i * 4 + nsub;
        float v = __half2float(oh[((size_t)node << 6) + c]);
        su += v;
        sq += v * v;
    }
    s1[t] = su;
    s2[t] = sq;
    __syncthreads();
    if (t < 64) {
        float a = s1[t] + s1[t + 64] + s1[t + 128] + s1[t + 192];
        float b = s2[t] + s2[t + 64] + s2[t + 128] + s2[t + 192];
        atomicAdd(&bnsum[t], a);
        atomicAdd(&bnsq[t], b);
    }
}

__global__ void k_bnf(const float* bnsum, const float* bnsq, const float* gamma,
                      const float* beta, float* bnab) {
    int c = threadIdx.x;
    float mean = bnsum[c] * (1.f / N_NODES);
    float var = bnsq[c] * (1.f / N_NODES) - mean * mean;
    float A = gamma[c] * rsqrtf(var + 1e-5f);
    bnab[c] = A;
    bnab[64 + c] = beta[c] - mean * A;
}

__global__ void k_bna(const __half* __restrict__ oh, const float* __restrict__ bnab,
                      __half* __restrict__ hh) {
    int idx = blockIdx.x * 256 + threadIdx.x;
    int c = idx & 63;
    float v = lrelu(__half2float(oh[idx]) * bnab[c] + bnab[64 + c]);
    hh[idx] = __float2half(v);
}

// ---------------- qmod/ext projection via MFMA (iteration 0 only) ----------
__global__ __launch_bounds__(256) void k_gemm(
    const __half* __restrict__ oh, const __half* __restrict__ hhin,
    const __half* __restrict__ wp, const float* __restrict__ bcomb,
    const float* __restrict__ bnab, int use_bn,
    __half* __restrict__ qh, float* __restrict__ ext, __half* __restrict__ hhout) {
    __shared__ __half qsm[64 * 68];
    int tid = threadIdx.x;
    int w = tid >> 6;
    int lane = tid & 63;
    int nloc = lane & 15;
    int kg = lane >> 4;
    int base = blockIdx.x * 64;

    half8_t A[2], AE[2];
    const half8_t* wpv = (const half8_t*)wp;
#pragma unroll
    for (int kh = 0; kh < 2; kh++) A[kh] = wpv[((w << 1) + kh) * 64 + lane];
    if (w == 3) {
#pragma unroll
        for (int kh = 0; kh < 2; kh++) AE[kh] = wpv[((8 << 1) + kh) * 64 + lane];
    }

    half8_t z8;
#pragma unroll
    for (int i = 0; i < 8; i++) z8[i] = (_Float16)0.f;

    half8_t B[4][2];
    int n[4];
    bool g[4];
#pragma unroll
    for (int nf = 0; nf < 4; nf++) {
        n[nf] = base + (nf << 4) + nloc;
        g[nf] = n[nf] < N_NODES;
    }

    if (use_bn) {
        float4 bnA[2][2], bnB[2][2];
#pragma unroll
        for (int kh = 0; kh < 2; kh++) {
            int k0 = (kh << 5) + (kg << 3);
            bnA[kh][0] = *(const float4*)&bnab[k0];
            bnA[kh][1] = *(const float4*)&bnab[k0 + 4];
            bnB[kh][0] = *(const float4*)&bnab[64 + k0];
            bnB[kh][1] = *(const float4*)&bnab[64 + k0 + 4];
        }
        const int4 zi4 = make_int4(0, 0, 0, 0);
#pragma unroll
        for (int nf = 0; nf < 4; nf++) {
            const __half* orow = oh + ((size_t)n[nf] << 6);
#pragma unroll
            for (int kh = 0; kh < 2; kh++) {
                int k0 = (kh << 5) + (kg << 3);
                int4 raw = g[nf] ? *(const int4*)&orow[k0] : zi4;
                const __half2* op = (const __half2*)&raw;
                float2 o01 = __half22float2(op[0]);
                float2 o23 = __half22float2(op[1]);
                float2 o45 = __half22float2(op[2]);
                float2 o67 = __half22float2(op[3]);
                float4 lo, hi;
                lo.x = lrelu(o01.x * bnA[kh][0].x + bnB[kh][0].x);
                lo.y = lrelu(o01.y * bnA[kh][0].y + bnB[kh][0].y);
                lo.z = lrelu(o23.x * bnA[kh][0].z + bnB[kh][0].z);
                lo.w = lrelu(o23.y * bnA[kh][0].w + bnB[kh][0].w);
                hi.x = lrelu(o45.x * bnA[kh][1].x + bnB[kh][1].x);
                hi.y = lrelu(o45.y * bnA[kh][1].y + bnB[kh][1].y);
                hi.z = lrelu(o67.x * bnA[kh][1].z + bnB[kh][1].z);
                hi.w = lrelu(o67.y * bnA[kh][1].w + bnB[kh][1].w);
                half8_t r;
                r[0] = (_Float16)lo.x; r[1] = (_Float16)lo.y;
                r[2] = (_Float16)lo.z; r[3] = (_Float16)lo.w;
                r[4] = (_Float16)hi.x; r[5] = (_Float16)hi.y;
                r[6] = (_Float16)hi.z; r[7] = (_Float16)hi.w;
                B[nf][kh] = r;
                if (g[nf]) *(half8_t*)&hhout[((size_t)n[nf] << 6) + k0] = r;
            }
        }
    } else {
#pragma unroll
        for (int nf = 0; nf < 4; nf++) {
#pragma unroll
            for (int kh = 0; kh < 2; kh++) {
                int k0 = (kh << 5) + (kg << 3);
                B[nf][kh] = g[nf] ? *(const half8_t*)&hhin[((size_t)n[nf] << 6) + k0]
                                  : z8;
            }
        }
    }

    f32x4 acc[4], accE[4];
#pragma unroll
    for (int nf = 0; nf < 4; nf++) {
        acc[nf] = (f32x4){0.f, 0.f, 0.f, 0.f};
        accE[nf] = (f32x4){0.f, 0.f, 0.f, 0.f};
    }

#pragma unroll
    for (int nf = 0; nf < 4; nf++) {
        acc[nf] = __builtin_amdgcn_mfma_f32_16x16x32_f16(A[0], B[nf][0], acc[nf],
                                                          0, 0, 0);
        acc[nf] = __builtin_amdgcn_mfma_f32_16x16x32_f16(A[1], B[nf][1], acc[nf],
                                                          0, 0, 0);
    }
    if (w == 3) {
#pragma unroll
        for (int nf = 0; nf < 4; nf++) {
            accE[nf] = __builtin_amdgcn_mfma_f32_16x16x32_f16(AE[0], B[nf][0],
                                                              accE[nf], 0, 0, 0);
            accE[nf] = __builtin_amdgcn_mfma_f32_16x16x32_f16(AE[1], B[nf][1],
                                                              accE[nf], 0, 0, 0);
        }
    }

    int rowg = kg << 2;
    int c0 = (w << 4) + rowg;
    float4 bi = *(const float4*)&bcomb[c0];
#pragma unroll
    for (int nf = 0; nf < 4; nf++) {
        int nl = (nf << 4) + nloc;
        __half2 p0 = __floats2half2_rn(acc[nf][0] + bi.x, acc[nf][1] + bi.y);
        __half2 p1 = __floats2half2_rn(acc[nf][2] + bi.z, acc[nf][3] + bi.w);
        *(__half2*)&qsm[nl * 68 + c0] = p0;
        *(__half2*)&qsm[nl * 68 + c0 + 2] = p1;
    }
    if (w == 3 && kg == 0) {
        float4 be = *(const float4*)&bcomb[128];
#pragma unroll
        for (int nf = 0; nf < 4; nf++) {
            if (!g[nf]) continue;
            float4 r;
            r.x = accE[nf][0] + be.x;
            r.y = accE[nf][1] + be.y;
            r.z = accE[nf][2] + be.z;
            r.w = accE[nf][3] + be.w;
            *(float4*)&ext[(size_t)n[nf] << 2] = r;
        }
    }
    __syncthreads();
#pragma unroll
    for (int rep = 0; rep < 8; rep++) {
        int i = rep * 256 + tid;
        int row = i >> 5;
        int col = (i & 31) << 1;
        if (base + row < N_NODES) {
            int v = *(int*)&qsm[row * 68 + col];
            *(int*)&qh[((size_t)(base + row) << 6) + col] = v;
        }
    }
}

// ---------------- fused iteration: aggH + proj + (next-gemm | MLP) ----------------
// Round-6 post-mortem: the 20KB LDS `red` transpose (lane-stride 20 words ->
// 8-way bank conflicts, 3.4M cycles) capped occupancy at 5 blocks/CU; nothing
// was >41% busy (latency-bound gather). Fix: register butterfly over the 4
// edge-slot lane bits (lane (es,cl) ends holding channel cl*16+bitrev4(es)),
// LDS 30.7KB -> 19.5KB -> 8 blocks/CU. LAST templated so the f32 epilogue
// doesn't penalize the other two dispatches.
template <int LAST>
__global__ __launch_bounds__(256, LAST ? 4 : 8) void k_fused(
    __half* qh, float* ext,                     // in-place: own rows read then written
    const __half* __restrict__ hh_in, __half* __restrict__ hh_out,
    const int* __restrict__ idx, const int2* __restrict__ csr,
    const __half* __restrict__ wp, const __half* __restrict__ wvp,
    const float* __restrict__ We, const float* __restrict__ bv,
    const float* __restrict__ bcomb,
    const float* __restrict__ Wf1, const float* __restrict__ bf1,
    const float* __restrict__ Wf2, const float* __restrict__ bf2v,
    const float* __restrict__ mask, float* __restrict__ out,
    int bucket) {
    constexpr int RSM_BYTES = LAST ? (64 * 68 * 4) : (64 * 72 * 2);
    __shared__ __align__(16) char smem[RSM_BYTES + 9216 + 1024];
    __half* rsm16 = (__half*)smem;                // phase 2/3a: r f16 [64][72]
    float* rsm32 = (float*)smem;                  // phase 2/3b: r f32 [64][68]
    __half* Shatsm = (__half*)(smem + RSM_BYTES); // phase 1/2: [64][72] f16
    __half* qsm = (__half*)(smem + RSM_BYTES);    // phase 3a reuse
    float* W1sm = (float*)(smem + RSM_BYTES);     // phase 3b reuse [64][32]
    float4* svecsm = (float4*)(smem + RSM_BYTES + 9216);  // [64]

    int tid = threadIdx.x;
    int wv = tid >> 6;
    int lane = tid & 63;
    int base = blockIdx.x * 64;

    // ---- phase 1: aggregation; wave wv owns nodes base+wv*16 .. +15 ----
    {
        int es = lane >> 2, cl = lane & 3;
        // final channel after butterfly: cl*16 + bitrev4(es)
        int jf = ((es & 1) << 3) | ((es & 2) << 1) | ((es & 4) >> 1) | ((es & 8) >> 3);
        int shatcol = (cl << 4) + jf;
        for (int nl = 0; nl < 16; nl++) {
            int node = base + (wv << 4) + nl;
            if (node >= N_NODES) continue;   // wave-uniform
            float4 ex = *(const float4*)&ext[(size_t)node << 2];
            float beta = ex.x, qe0 = ex.y, qe1 = ex.z;
            int4 qr0 = *(const int4*)&qh[((size_t)node << 6) + (cl << 4)];
            int4 qr1 = *(const int4*)&qh[((size_t)node << 6) + (cl << 4) + 8];
            const half2_t* qp0 = (const half2_t*)&qr0;
            const half2_t* qp1 = (const half2_t*)&qr1;

            float l = 0.f, sA = 0.f, sB = 0.f;
            float accv[16];
#pragma unroll
            for (int c = 0; c < 16; c++) accv[c] = 0.f;

            int nEdge, rbase2;
            if (bucket) {
                nEdge = idx[node];
                rbase2 = node << 6;
            } else {
                rbase2 = idx[node];
                nEdge = idx[node + 1] - rbase2;
            }
            int nIter = (nEdge + 15) >> 4;

            auto body = [&](int4 h0, int4 h1, int2 rec, bool ok) {
                const half2_t* hp0 = (const half2_t*)&h0;
                const half2_t* hp1 = (const half2_t*)&h1;
                float t = 0.f;
#if __has_builtin(__builtin_amdgcn_fdot2)
#pragma unroll
                for (int p = 0; p < 4; p++)
                    t = __builtin_amdgcn_fdot2(hp0[p], qp0[p], t, false);
#pragma unroll
                for (int p = 0; p < 4; p++)
                    t = __builtin_amdgcn_fdot2(hp1[p], qp1[p], t, false);
#else
                const __half* hq0 = (const __half*)&qr0;
                const __half* hq1 = (const __half*)&qr1;
                const __half* hh0 = (const __half*)&h0;
                const __half* hh1 = (const __half*)&h1;
#pragma unroll
                for (int c = 0; c < 8; c++)
                    t += __half2float(hh0[c]) * __half2float(hq0[c]);
#pragma unroll
                for (int c = 0; c < 8; c++)
                    t += __half2float(hh1[c]) * __half2float(hq1[c]);
#endif
                t += __shfl_xor(t, 1, 64);
                t += __shfl_xor(t, 2, 64);
                float2 ef = __half22float2(*(__half2*)&rec.y);
                t += beta + ef.x * qe0 + ef.y * qe1;
                float pp = ok ? __expf(t) : 0.f;
                l += pp;
                sA += pp * ef.x;
                sB += pp * ef.y;
                const __half* hs0 = (const __half*)&h0;
                const __half* hs1 = (const __half*)&h1;
#pragma unroll
                for (int c = 0; c < 8; c++) accv[c] += pp * __half2float(hs0[c]);
#pragma unroll
                for (int c = 0; c < 8; c++) accv[8 + c] += pp * __half2float(hs1[c]);
            };

            if (bucket) {
                int2 recs[4];
#pragma unroll
                for (int i = 0; i < 4; i++) {
                    int e = (i << 4) + es;
                    recs[i] = (e < nEdge) ? csr[(size_t)rbase2 + e] : make_int2(0, 0);
                }
                if (nIter > 0) {
                    int src0 = recs[0].x & 0xFFFFF;
                    const __half* hr = hh_in + ((size_t)src0 << 6) + (cl << 4);
                    int4 h0c = *(const int4*)&hr[0];
                    int4 h1c = *(const int4*)&hr[8];
#pragma unroll
                    for (int i = 0; i < 4; i++) {
                        if (i < nIter) {
                            int4 h0 = h0c, h1 = h1c;
                            if (i + 1 < nIter) {
                                int srcn = recs[i + 1].x & 0xFFFFF;
                                const __half* hrn =
                                    hh_in + ((size_t)srcn << 6) + (cl << 4);
                                h0c = *(const int4*)&hrn[0];
                                h1c = *(const int4*)&hrn[8];
                            }
                            body(h0, h1, recs[i], ((i << 4) + es) < nEdge);
                        }
                    }
                }
            } else {
                for (int i = 0; i < nIter; i++) {
                    int e = (i << 4) + es;
                    bool ok = e < nEdge;
                    int2 rec = ok ? csr[(size_t)rbase2 + e] : make_int2(0, 0);
                    int src = rec.x & 0xFFFFF;
                    const __half* hr = hh_in + ((size_t)src << 6) + (cl << 4);
                    int4 h0 = *(const int4*)&hr[0];
                    int4 h1 = *(const int4*)&hr[8];
                    body(h0, h1, rec, ok);
                }
            }

#pragma unroll
            for (int D = 4; D < 64; D <<= 1) {
                l += __shfl_xor(l, D, 64);
                sA += __shfl_xor(sA, D, 64);
                sB += __shfl_xor(sB, D, 64);
            }
            float inv = 1.f / (l + 1e-16f);

            // register butterfly over edge-slot lane bits: keep-half exchange.
            // after step on bit b, remaining channel set is halved; lane sends
            // the half its partner keeps (send = up ? lo : hi).
#pragma unroll
            for (int step = 0; step < 4; step++) {
                int m = 4 << step;
                int half = 8 >> step;
                bool up = (lane & m) != 0;
#pragma unroll
                for (int i = 0; i < half; i++) {
                    float send = up ? accv[i] : accv[i + half];
                    float recv = __shfl_xor(send, m, 64);
                    float keep = up ? accv[i + half] : accv[i];
                    accv[i] = keep + recv;
                }
            }
            // 64 lanes -> 64 distinct channels: 2 halves/bank, conflict-free
            Shatsm[((wv << 4) + nl) * 72 + shatcol] = __float2half(accv[0] * inv);
            if (lane == 0)
                svecsm[(wv << 4) + nl] = make_float4(sA * inv, sB * inv, l * inv, 0.f);
        }
    }
    __syncthreads();   // Shatsm/svecsm complete; ext/qh fully read

    // ---- phase 2: proj -> r (into rsm) ----
    {
        int nloc = lane & 15, kg = lane >> 4;
        const half8_t* wvv = (const half8_t*)wvp;
        const half8_t* wpv = (const half8_t*)wp;
        half8_t Av0 = wvv[((wv << 1) + 0) * 64 + lane];
        half8_t Av1 = wvv[((wv << 1) + 1) * 64 + lane];
        half8_t As0 = wpv[(((4 + wv) << 1) + 0) * 64 + lane];
        half8_t As1 = wpv[(((4 + wv) << 1) + 1) * 64 + lane];

        int rowg = kg << 2;
        int c0 = (wv << 4) + rowg;
        float4 we0 = *(const float4*)&We[c0];
        float4 we1 = *(const float4*)&We[64 + c0];
        float4 bv4 = *(const float4*)&bv[c0];
        float4 bs4 = *(const float4*)&bcomb[64 + c0];

        half8_t z8;
#pragma unroll
        for (int i = 0; i < 8; i++) z8[i] = (_Float16)0.f;

#pragma unroll
        for (int nf = 0; nf < 4; nf++) {
            int n = base + (nf << 4) + nloc;
            bool g = n < N_NODES;
            int nl2 = (nf << 4) + nloc;
            const __half* srow = &Shatsm[nl2 * 72];
            const __half* hrow = hh_in + ((size_t)n << 6);
            half8_t Bs0 = g ? *(const half8_t*)&srow[kg << 3] : z8;
            half8_t Bs1 = g ? *(const half8_t*)&srow[32 + (kg << 3)] : z8;
            half8_t Bh0 = g ? *(const half8_t*)&hrow[kg << 3] : z8;
            half8_t Bh1 = g ? *(const half8_t*)&hrow[32 + (kg << 3)] : z8;

            f32x4 acc = (f32x4){0.f, 0.f, 0.f, 0.f};
            acc = __builtin_amdgcn_mfma_f32_16x16x32_f16(Av0, Bs0, acc, 0, 0, 0);
            acc = __builtin_amdgcn_mfma_f32_16x16x32_f16(Av1, Bs1, acc, 0, 0, 0);
            acc = __builtin_amdgcn_mfma_f32_16x16x32_f16(As0, Bh0, acc, 0, 0, 0);
            acc = __builtin_amdgcn_mfma_f32_16x16x32_f16(As1, Bh1, acc, 0, 0, 0);

            float4 sv = g ? svecsm[nl2] : make_float4(0.f, 0.f, 0.f, 0.f);
            float4 r;
            r.x = lrelu(acc[0] + sv.x * we0.x + sv.y * we1.x + sv.z * bv4.x + bs4.x);
            r.y = lrelu(acc[1] + sv.x * we0.y + sv.y * we1.y + sv.z * bv4.y + bs4.y);
            r.z = lrelu(acc[2] + sv.x * we0.z + sv.y * we1.z + sv.z * bv4.z + bs4.z);
            r.w = lrelu(acc[3] + sv.x * we0.w + sv.y * we1.w + sv.z * bv4.w + bs4.w);

            if (LAST) {
                *(float4*)&rsm32[nl2 * 68 + c0] = r;
            } else {
                __half2 p0 = __floats2half2_rn(r.x, r.y);
                __half2 p1 = __floats2half2_rn(r.z, r.w);
                *(__half2*)&rsm16[nl2 * 72 + c0] = p0;
                *(__half2*)&rsm16[nl2 * 72 + c0 + 2] = p1;
            }
        }
    }
    __syncthreads();   // rsm complete; Shatsm region free

    if (!LAST) {
        // ---- phase 3a: next iteration's qmod/ext from r ----
        int nloc = lane & 15, kg = lane >> 4;
        const half8_t* wpv = (const half8_t*)wp;
        half8_t A0 = wpv[((wv << 1) + 0) * 64 + lane];
        half8_t A1 = wpv[((wv << 1) + 1) * 64 + lane];
        half8_t AE0 = A0, AE1 = A1;
        if (wv == 3) {
            AE0 = wpv[16 * 64 + lane];
            AE1 = wpv[17 * 64 + lane];
        }
        int rowg = kg << 2;
        int c0 = (wv << 4) + rowg;
        float4 bi = *(const float4*)&bcomb[c0];

#pragma unroll
        for (int nf = 0; nf < 4; nf++) {
            int nl2 = (nf << 4) + nloc;
            const __half* rrow = &rsm16[nl2 * 72];
            half8_t B0 = *(const half8_t*)&rrow[kg << 3];
            half8_t B1 = *(const half8_t*)&rrow[32 + (kg << 3)];
            f32x4 acc = (f32x4){0.f, 0.f, 0.f, 0.f};
            acc = __builtin_amdgcn_mfma_f32_16x16x32_f16(A0, B0, acc, 0, 0, 0);
            acc = __builtin_amdgcn_mfma_f32_16x16x32_f16(A1, B1, acc, 0, 0, 0);
            __half2 p0 = __floats2half2_rn(acc[0] + bi.x, acc[1] + bi.y);
            __half2 p1 = __floats2half2_rn(acc[2] + bi.z, acc[3] + bi.w);
            *(__half2*)&qsm[nl2 * 72 + c0] = p0;
            *(__half2*)&qsm[nl2 * 72 + c0 + 2] = p1;
            if (wv == 3) {
                f32x4 ae = (f32x4){0.f, 0.f, 0.f, 0.f};
                ae = __builtin_amdgcn_mfma_f32_16x16x32_f16(AE0, B0, ae, 0, 0, 0);
                ae = __builtin_amdgcn_mfma_f32_16x16x32_f16(AE1, B1, ae, 0, 0, 0);
                if (kg == 0) {
                    int n = base + nl2;
                    if (n < N_NODES) {
                        float4 be = *(const float4*)&bcomb[128];
                        float4 r;
                        r.x = ae[0] + be.x;
                        r.y = ae[1] + be.y;
                        r.z = ae[2] + be.z;
                        r.w = ae[3] + be.w;
                        *(float4*)&ext[(size_t)n << 2] = r;
                    }
                }
            }
        }
        __syncthreads();
        // coalesced row writes: qh (from qsm) + hh_out (from rsm16)
#pragma unroll
        for (int rep = 0; rep < 8; rep++) {
            int i = rep * 256 + tid;
            int row = i >> 5;
            int col = (i & 31) << 1;
            if (base + row < N_NODES) {
                *(int*)&qh[((size_t)(base + row) << 6) + col] =
                    *(int*)&qsm[row * 72 + col];
                *(int*)&hh_out[((size_t)(base + row) << 6) + col] =
                    *(int*)&rsm16[row * 72 + col];
            }
        }
    } else {
        // ---- phase 3b: fused MLP 64->32->1, * mask ----
        for (int i = tid; i < 2048; i += 256) W1sm[i] = Wf1[i];
        __syncthreads();
        int nl2 = tid >> 2, jg = tid & 3;
        int node = base + nl2;
        float a8[8];
        const float* b1p = &bf1[jg << 3];
#pragma unroll
        for (int k = 0; k < 8; k++) a8[k] = b1p[k];
        const float* hr = &rsm32[nl2 * 68];
        for (int c = 0; c < 64; c++) {
            float hv = hr[c];
            const float* wr = &W1sm[(c << 5) + (jg << 3)];
            float4 wa = *(const float4*)&wr[0];
            float4 wb = *(const float4*)&wr[4];
            a8[0] += hv * wa.x; a8[1] += hv * wa.y;
            a8[2] += hv * wa.z; a8[3] += hv * wa.w;
            a8[4] += hv * wb.x; a8[5] += hv * wb.y;
            a8[6] += hv * wb.z; a8[7] += hv * wb.w;
        }
        const float* w2p = &Wf2[jg << 3];
        float zs = 0.f;
#pragma unroll
        for (int k = 0; k < 8; k++) zs += lrelu(a8[k]) * w2p[k];
        zs += __shfl_xor(zs, 1, 64);
        zs += __shfl_xor(zs, 2, 64);
        if (jg == 0 && node < N_NODES)
            out[node] = (zs + bf2v[0]) * mask[node];
    }
}

extern "C" void kernel_launch(void* const* d_in, const int* in_sizes, int n_in,
                              void* d_out, int out_size, void* d_ws, size_t ws_size,
                              hipStream_t stream) {
    const float* x = (const float*)d_in[0];
    const int* ei = (const int*)d_in[1];
    const float* ea = (const float*)d_in[2];
    const float* mask = (const float*)d_in[3];
    const float *Wq1 = (const float*)d_in[4], *bq1 = (const float*)d_in[5];
    const float *Wk1 = (const float*)d_in[6], *bk1 = (const float*)d_in[7];
    const float *Wv1 = (const float*)d_in[8], *bv1 = (const float*)d_in[9];
    const float *We1 = (const float*)d_in[10];
    const float *Ws1 = (const float*)d_in[11], *bs1 = (const float*)d_in[12];
    const float *Wq2 = (const float*)d_in[13], *bq2 = (const float*)d_in[14];
    const float *Wk2 = (const float*)d_in[15], *bk2 = (const float*)d_in[16];
    const float *Wv2 = (const float*)d_in[17], *bv2 = (const float*)d_in[18];
    const float *We2 = (const float*)d_in[19];
    const float *Ws2 = (const float*)d_in[20], *bs2 = (const float*)d_in[21];
    const float *gamma = (const float*)d_in[22], *beta = (const float*)d_in[23];
    const float *Wf1 = (const float*)d_in[24], *bf1 = (const float*)d_in[25];
    const float *Wf2 = (const float*)d_in[26], *bf2v = (const float*)d_in[27];
    float* out = (float*)d_out;

    const size_t bucket_need =
        (size_t)NB_BKT * BCAP * 8 + (size_t)N_NODES * 64 * 8 +
        (size_t)N_NODES * 64 * 2 * 4 +   // qh, oh, hh0, hh1 (f16)
        (size_t)N_NODES * 16 +           // ext
        (size_t)N_NODES * 4 * 3 + (1 << 20);
    bool use_bucket = ws_size >= bucket_need;

    char* ws = (char*)d_ws;
    size_t off = 0;
    auto alloc = [&](size_t b) {
        size_t r = off;
        off += (b + 255) & ~(size_t)255;
        return r;
    };
    int* deg = (int*)(ws + alloc(N_NODES * 4));
    int* fill = (int*)(ws + alloc(N_NODES * 4));
    int* rowptr = (int*)(ws + alloc((N_NODES + 1) * 4));
    int* bsum = (int*)(ws + alloc(SCAN_B * 4));
    int* gCur = (int*)(ws + alloc(NB_BKT * 4));
    float* bnsum = (float*)(ws + alloc(64 * 4));
    float* bnsq = (float*)(ws + alloc(64 * 4));
    float* bnab = (float*)(ws + alloc(128 * 4));
    float* Wcomb = (float*)(ws + alloc(9216 * 4));
    float* bcomb = (float*)(ws + alloc(160 * 4));
    __half* wp = (__half*)(ws + alloc(9216 * 2));
    __half* wvp = (__half*)(ws + alloc(4096 * 2));
    float* ext = (float*)(ws + alloc((size_t)N_NODES * 16));
    int2* bin1 = (int2*)(ws + alloc(use_bucket ? (size_t)NB_BKT * BCAP * 8 : 256));
    int2* csr = (int2*)(ws + alloc(use_bucket ? (size_t)N_NODES * 64 * 8
                                              : (size_t)N_EDGES * 8));
    __half* qh = (__half*)(ws + alloc((size_t)N_NODES * 64 * 2));
    __half* oh = (__half*)(ws + alloc((size_t)N_NODES * 64 * 2));
    __half* hh0 = (__half*)(ws + alloc((size_t)N_NODES * 64 * 2));
    __half* hh1 = (__half*)(ws + alloc((size_t)N_NODES * 64 * 2));

    const int* srcI = ei;
    const int* tgtI = ei + N_EDGES;

    hipMemsetAsync(bnsum, 0, 64 * 4, stream);
    hipMemsetAsync(bnsq, 0, 64 * 4, stream);

    k_prep2<<<36, 256, 0, stream>>>(Wq2, Wk2, Ws2, We2, bk2, Wcomb);
    k_prepb<<<1, 192, 0, stream>>>(Wk2, We2, bq2, bk2, bs2, Wq1, Wk1, We1, bq1, bk1,
                                   bcomb);
    k_prepw<<<36, 256, 0, stream>>>(Wcomb, wp);
    k_prepv<<<16, 256, 0, stream>>>(Wv2, wvp);

    const int* aggIdx;
    if (use_bucket) {
        hipMemsetAsync(gCur, 0, NB_BKT * 4, stream);
        k_bin1<<<250, 256, 0, stream>>>(srcI, tgtI, (const float2*)ea, gCur, bin1);
        k_bin2<<<NB_BKT, 256, 0, stream>>>(gCur, bin1, csr, fill);
        aggIdx = fill;
    } else {
        hipMemsetAsync(deg, 0, N_NODES * 4, stream);
        k_count<<<N_EDGES / 256, 256, 0, stream>>>(tgtI, deg);
        k_scan1<<<SCAN_B, 256, 0, stream>>>(deg, bsum);
        k_scan2<<<1, 64, 0, stream>>>(bsum, rowptr);
        k_scan3<<<SCAN_B, 256, 0, stream>>>(deg, bsum, rowptr, fill);
        k_scatter<<<N_EDGES / 256, 256, 0, stream>>>(srcI, tgtI, (const float2*)ea,
                                                     fill, csr);
        aggIdx = rowptr;
    }
    int bkt = use_bucket ? 1 : 0;

    k_agg1<<<N_NODES / 4, 256, 0, stream>>>(x, aggIdx, csr, Wv1, We1, Ws1, bv1, bs1,
                                            bcomb + 144, oh, bkt);
    k_bnp<<<250, 256, 0, stream>>>(oh, bnsum, bnsq);
    k_bnf<<<1, 64, 0, stream>>>(bnsum, bnsq, gamma, beta, bnab);
    if (!use_bucket)
        k_bna<<<N_NODES * 64 / 256, 256, 0, stream>>>(oh, bnab, hh0);

    const int gemm_grid = (N_NODES + 63) / 64;
    // g0: qmod/ext for iteration 1; writes hh0 = h_a (BN'd h) in bucket path
    k_gemm<<<gemm_grid, 256, 0, stream>>>(oh, hh0, wp, bcomb, bnab, bkt, qh, ext,
                                          hh0);
    // F0/F1: aggregate+proj+next-gemm; F2: aggregate+proj+MLP -> out
    k_fused<0><<<gemm_grid, 256, 0, stream>>>(qh, ext, hh0, hh1, aggIdx, csr, wp,
                                              wvp, We2, bv2, bcomb, Wf1, bf1, Wf2,
                                              bf2v, mask, out, bkt);
    k_fused<0><<<gemm_grid, 256, 0, stream>>>(qh, ext, hh1, hh0, aggIdx, csr, wp,
                                              wvp, We2, bv2, bcomb, Wf1, bf1, Wf2,
                                              bf2v, mask, out, bkt);
    k_fused<1><<<gemm_grid, 256, 0, stream>>>(qh, ext, hh0, hh1, aggIdx, csr, wp,
                                              wvp, We2, bv2, bcomb, Wf1, bf1, Wf2,
                                              bf2v, mask, out, bkt);
}

// Round 8
// 531.872 us; speedup vs baseline: 1.1515x; 1.1515x over previous
//
#include <hip/hip_runtime.h>
#include <hip/hip_fp16.h>

#define N_NODES 100000
#define N_EDGES 1600000
#define SCAN_B ((N_NODES + 1023) / 1024)
#define BSHIFT 7
#define NB_BKT ((N_NODES + 127) / 128)   // 782
#define BCAP 2560                        // mean 2048, +11 sigma

typedef _Float16 half2_t __attribute__((ext_vector_type(2)));
typedef _Float16 half8_t __attribute__((ext_vector_type(8)));
typedef float f32x4 __attribute__((ext_vector_type(4)));

__device__ __forceinline__ float lrelu(float x) { return x >= 0.f ? x : 0.01f * x; }

// ---------------- dense CSR build (fallback when ws is small) ----------------
__global__ void k_count(const int* __restrict__ tgt, int* __restrict__ deg) {
    int i = blockIdx.x * 256 + threadIdx.x;
    atomicAdd(&deg[tgt[i]], 1);
}

__global__ void k_scan1(const int* __restrict__ deg, int* __restrict__ bsum) {
    __shared__ int s[256];
    int t = threadIdx.x;
    int gi = blockIdx.x * 1024 + t * 4;
    int v = 0;
    if (gi < N_NODES) {
        int4 d = *(const int4*)&deg[gi];
        v = d.x + d.y + d.z + d.w;
    }
    s[t] = v;
    __syncthreads();
    for (int d = 128; d > 0; d >>= 1) {
        if (t < d) s[t] += s[t + d];
        __syncthreads();
    }
    if (t == 0) bsum[blockIdx.x] = s[0];
}

__global__ void k_scan2(int* bsum, int* rowptr) {
    if (threadIdx.x == 0) {
        int run = 0;
        for (int b = 0; b < SCAN_B; b++) {
            int v = bsum[b];
            bsum[b] = run;
            run += v;
        }
        rowptr[N_NODES] = run;
    }
}

__global__ void k_scan3(const int* __restrict__ deg, const int* __restrict__ bsum,
                        int* __restrict__ rowptr, int* __restrict__ fill) {
    __shared__ int s[256];
    int t = threadIdx.x;
    int gi = blockIdx.x * 1024 + t * 4;
    int4 d = make_int4(0, 0, 0, 0);
    if (gi < N_NODES) d = *(const int4*)&deg[gi];
    int tsum = d.x + d.y + d.z + d.w;
    s[t] = tsum;
    __syncthreads();
    for (int dd = 1; dd < 256; dd <<= 1) {
        int val = (t >= dd) ? s[t - dd] : 0;
        __syncthreads();
        s[t] += val;
        __syncthreads();
    }
    int texcl = s[t] - tsum + bsum[blockIdx.x];
    if (gi < N_NODES) {
        int4 w;
        w.x = texcl;
        w.y = texcl + d.x;
        w.z = texcl + d.x + d.y;
        w.w = texcl + d.x + d.y + d.z;
        *(int4*)&rowptr[gi] = w;
        *(int4*)&fill[gi] = w;
    }
}

__global__ void k_scatter(const int* __restrict__ src, const int* __restrict__ tgt,
                          const float2* __restrict__ ea,
                          int* __restrict__ fill, int2* __restrict__ csr) {
    int i = blockIdx.x * 256 + threadIdx.x;
    int t = tgt[i];
    float2 e = ea[i];
    int pos = atomicAdd(&fill[t], 1);
    __half2 h2 = __floats2half2_rn(e.x, e.y);
    csr[pos] = make_int2(src[i], *(int*)&h2);
}

// ---------------- two-level binning (bucket path) ----------------
__global__ __launch_bounds__(256) void k_bin1(const int* __restrict__ src,
                                              const int* __restrict__ tgt,
                                              const float2* __restrict__ ea,
                                              int* __restrict__ gCur,
                                              int2* __restrict__ bin) {
    __shared__ int hist[NB_BKT];
    __shared__ int cur[NB_BKT];
    int tid = threadIdx.x;
    for (int b = tid; b < NB_BKT; b += 256) hist[b] = 0;
    __syncthreads();
    int base = blockIdx.x * 6400;
#pragma unroll 5
    for (int k = 0; k < 25; k++) {
        int i = base + k * 256 + tid;
        atomicAdd(&hist[tgt[i] >> BSHIFT], 1);
    }
    __syncthreads();
    for (int b = tid; b < NB_BKT; b += 256)
        cur[b] = atomicAdd(&gCur[b], hist[b]);
    __syncthreads();
    for (int k = 0; k < 25; k++) {
        int i = base + k * 256 + tid;
        int t = tgt[i];
        int b = t >> BSHIFT;
        float2 e = ea[i];
        int pos = atomicAdd(&cur[b], 1);
        if (pos < BCAP) {
            __half2 h2 = __floats2half2_rn(e.x, e.y);
            int2 rec;
            rec.x = src[i] | ((t & 127) << 20);
            rec.y = *(int*)&h2;
            bin[(size_t)b * BCAP + pos] = rec;
        }
    }
}

__global__ __launch_bounds__(256) void k_bin2(const int* __restrict__ gCnt,
                                              const int2* __restrict__ bin,
                                              int2* __restrict__ csr,
                                              int* __restrict__ fill) {
    __shared__ int cnt[128];
    int tid = threadIdx.x;
    if (tid < 128) cnt[tid] = 0;
    __syncthreads();
    int b = blockIdx.x;
    int nb = min(gCnt[b], BCAP);
    const int2* myb = &bin[(size_t)b * BCAP];
    for (int i = tid; i < nb; i += 256) {
        int2 rec = myb[i];
        int tloc = (rec.x >> 20) & 127;
        int s = rec.x & 0xFFFFF;
        int pos = atomicAdd(&cnt[tloc], 1);
        if (pos < 64) {
            int node = (b << BSHIFT) + tloc;
            csr[((size_t)node << 6) + pos] = make_int2(s | (rec.x & 0xFFF00000), rec.y);
        }
    }
    __syncthreads();
    if (tid < 128) {
        int node = (b << BSHIFT) + tid;
        if (node < N_NODES) fill[node] = min(cnt[tid], 64);
    }
}

// ---------------- weight precompute ----------------
// Wcomb[64 k][144 c]: c 0-63 qmod (=0.125*Wq2 Wk2^T), 64-127 Ws2, 128 beta (u2),
// 129-130 qe (G), 131-143 zero.
__global__ void k_prep2(const float* __restrict__ Wq, const float* __restrict__ Wk,
                        const float* __restrict__ Ws, const float* __restrict__ We,
                        const float* __restrict__ bk, float* __restrict__ Wcomb) {
    int idx = blockIdx.x * 256 + threadIdx.x;  // 0..9215
    if (idx >= 9216) return;
    int j = idx / 144;
    int m = idx - j * 144;
    float v = 0.f;
    if (m < 64) {
        float s = 0.f;
        for (int ch = 0; ch < 64; ch++) s += Wq[j * 64 + ch] * Wk[m * 64 + ch];
        v = 0.125f * s;
    } else if (m < 128) {
        v = Ws[j * 64 + (m - 64)];
    } else if (m == 128) {
        float s = 0.f;
        for (int ch = 0; ch < 64; ch++) s += Wq[j * 64 + ch] * bk[ch];
        v = 0.125f * s;
    } else if (m <= 130) {
        float s = 0.f;
        for (int ch = 0; ch < 64; ch++) s += Wq[j * 64 + ch] * We[(m - 129) * 64 + ch];
        v = 0.125f * s;
    }
    Wcomb[idx] = v;
}

// bcomb[0..143]: biases for the 144 output channels; bcomb[144..159]: layer-1 consts
__global__ void k_prepb(const float* __restrict__ Wk2, const float* __restrict__ We2,
                        const float* __restrict__ bq2, const float* __restrict__ bk2,
                        const float* __restrict__ bs2, const float* __restrict__ Wq1,
                        const float* __restrict__ Wk1, const float* __restrict__ We1,
                        const float* __restrict__ bq1, const float* __restrict__ bk1,
                        float* __restrict__ bcomb) {
    int t = threadIdx.x;
    if (t >= 160) return;
    float v = 0.f;
    if (t < 64) {
        float s = 0.f;
        for (int i = 0; i < 64; i++) s += Wk2[t * 64 + i] * bq2[i];
        v = 0.125f * s;
    } else if (t < 128) {
        v = bs2[t - 64];
    } else if (t == 128) {
        float s = 0.f;
        for (int i = 0; i < 64; i++) s += bq2[i] * bk2[i];
        v = 0.125f * s;
    } else if (t <= 130) {
        float s = 0.f;
        for (int i = 0; i < 64; i++) s += bq2[i] * We2[(t - 129) * 64 + i];
        v = 0.125f * s;
    } else if (t < 144) {
        v = 0.f;
    } else {
        int t2 = t - 144;
        float s = 0.f;
        if (t2 < 4) {            // A1[j][m], j=t2>>1, m=t2&1
            int j = t2 >> 1, m = t2 & 1;
            for (int ch = 0; ch < 64; ch++) s += Wq1[j * 64 + ch] * Wk1[m * 64 + ch];
        } else if (t2 < 6) {     // u1[j]
            int j = t2 - 4;
            for (int ch = 0; ch < 64; ch++) s += Wq1[j * 64 + ch] * bk1[ch];
        } else if (t2 < 8) {     // w1[m]
            int m = t2 - 6;
            for (int ch = 0; ch < 64; ch++) s += bq1[ch] * Wk1[m * 64 + ch];
        } else if (t2 == 8) {    // c1
            for (int ch = 0; ch < 64; ch++) s += bq1[ch] * bk1[ch];
        } else if (t2 < 13) {    // B1[j][d]
            int j = (t2 - 9) >> 1, d = (t2 - 9) & 1;
            for (int ch = 0; ch < 64; ch++) s += Wq1[j * 64 + ch] * We1[d * 64 + ch];
        } else if (t2 < 15) {    // d1[d]
            int d = t2 - 13;
            for (int ch = 0; ch < 64; ch++) s += bq1[ch] * We1[d * 64 + ch];
        }
        v = 0.125f * s;
    }
    bcomb[t] = v;
}

// pack Wcomb into MFMA A-fragments: 9 M-frags x 2 kh x 64 lanes x 8 elems
__global__ void k_prepw(const float* __restrict__ Wcomb, __half* __restrict__ wp) {
    int t = blockIdx.x * 256 + threadIdx.x;  // 0..9215
    if (t >= 9216) return;
    int e = t & 7;
    int lane = (t >> 3) & 63;
    int kh = (t >> 9) & 1;
    int fm = t >> 10;  // 0..8
    int k = (kh << 5) + ((lane >> 4) << 3) + e;
    int c = fm * 16 + (lane & 15);
    wp[t] = __float2half(Wcomb[k * 144 + c]);
}

// pack Wv2 into MFMA A-fragments: 4 M-frags x 2 kh x 64 lanes x 8 elems
__global__ void k_prepv(const float* __restrict__ Wv, __half* __restrict__ wvp) {
    int t = blockIdx.x * 256 + threadIdx.x;  // 0..4095
    if (t >= 4096) return;
    int e = t & 7;
    int lane = (t >> 3) & 63;
    int kh = (t >> 9) & 1;
    int fm = t >> 10;  // 0..3
    int k = (kh << 5) + ((lane >> 4) << 3) + e;
    int c = fm * 16 + (lane & 15);
    wvp[t] = __float2half(Wv[k * 64 + c]);
}

// ---------------- layer 1 aggregation (2-dim trick): wave per node, lane per slot --
__global__ __launch_bounds__(256) void k_agg1(
    const float* __restrict__ x, const int* __restrict__ idx,
    const int2* __restrict__ csr, const float* __restrict__ Wv,
    const float* __restrict__ We, const float* __restrict__ Ws,
    const float* __restrict__ bv, const float* __restrict__ bs,
    const float* __restrict__ prep, __half* __restrict__ oh, int bucket) {
    int node = blockIdx.x * 4 + (threadIdx.x >> 6);
    int lane = threadIdx.x & 63;
    float2 xt = *(const float2*)&x[(size_t)node << 1];
    float a0 = xt.x * prep[0] + xt.y * prep[2] + prep[6];
    float a1 = xt.x * prep[1] + xt.y * prep[3] + prep[7];
    float b1 = xt.x * prep[4] + xt.y * prep[5] + prep[8];
    float g0 = xt.x * prep[9] + xt.y * prep[11] + prep[13];
    float g1 = xt.x * prep[10] + xt.y * prep[12] + prep[14];

    float l = 0.f, px0 = 0.f, px1 = 0.f, pA = 0.f, pB = 0.f;
    if (bucket) {
        int deg = idx[node];
        bool valid = lane < deg;
        int2 rec = valid ? csr[((size_t)node << 6) + lane] : make_int2(0, 0);
        int src = rec.x & 0xFFFFF;
        float2 ef = __half22float2(*(__half2*)&rec.y);
        float2 xs = valid ? *(const float2*)&x[(size_t)src << 1] : make_float2(0.f, 0.f);
        float t = a0 * xs.x + a1 * xs.y + b1 + g0 * ef.x + g1 * ef.y;
        float pp = valid ? __expf(t) : 0.f;
        l = pp;
        px0 = pp * xs.x;
        px1 = pp * xs.y;
        pA = pp * ef.x;
        pB = pp * ef.y;
    } else {
        int beg = idx[node], end = idx[node + 1];
        for (int p = beg + lane; p < end; p += 64) {
            int2 rec = csr[p];
            float2 ef = __half22float2(*(__half2*)&rec.y);
            float2 xs = *(const float2*)&x[(size_t)rec.x << 1];
            float t = a0 * xs.x + a1 * xs.y + b1 + g0 * ef.x + g1 * ef.y;
            float pp = __expf(t);
            l += pp;
            px0 += pp * xs.x;
            px1 += pp * xs.y;
            pA += pp * ef.x;
            pB += pp * ef.y;
        }
    }
#pragma unroll
    for (int D = 1; D < 64; D <<= 1) {
        l += __shfl_xor(l, D, 64);
        px0 += __shfl_xor(px0, D, 64);
        px1 += __shfl_xor(px1, D, 64);
        pA += __shfl_xor(pA, D, 64);
        pB += __shfl_xor(pB, D, 64);
    }
    float inv = 1.f / (l + 1e-16f);
    int c = lane;
    float r = (px0 * Wv[c] + px1 * Wv[64 + c] + pA * We[c] + pB * We[64 + c] +
               l * bv[c]) * inv +
              xt.x * Ws[c] + xt.y * Ws[64 + c] + bs[c];
    oh[((size_t)node << 6) + c] = __float2half(r);
}

// ---------------- batch norm ----------------
__global__ void k_bnp(const __half* __restrict__ oh, float* __restrict__ bnsum,
                      float* __restrict__ bnsq) {
    __shared__ float s1[256], s2[256];
    int t = threadIdx.x;
    int c = t & 63, nsub = t >> 6;
    float su = 0.f, sq = 0.f;
    int base = blockIdx.x * 400;
    for (int i = 0; i < 100; i++) {
        int node = base + i * 4 + nsub;
        float v = __half2float(oh[((size_t)node << 6) + c]);
        su += v;
        sq += v * v;
    }
    s1[t] = su;
    s2[t] = sq;
    __syncthreads();
    if (t < 64) {
        float a = s1[t] + s1[t + 64] + s1[t + 128] + s1[t + 192];
        float b = s2[t] + s2[t + 64] + s2[t + 128] + s2[t + 192];
        atomicAdd(&bnsum[t], a);
        atomicAdd(&bnsq[t], b);
    }
}

__global__ void k_bnf(const float* bnsum, const float* bnsq, const float* gamma,
                      const float* beta, float* bnab) {
    int c = threadIdx.x;
    float mean = bnsum[c] * (1.f / N_NODES);
    float var = bnsq[c] * (1.f / N_NODES) - mean * mean;
    float A = gamma[c] * rsqrtf(var + 1e-5f);
    bnab[c] = A;
    bnab[64 + c] = beta[c] - mean * A;
}

__global__ void k_bna(const __half* __restrict__ oh, const float* __restrict__ bnab,
                      __half* __restrict__ hh) {
    int idx = blockIdx.x * 256 + threadIdx.x;
    int c = idx & 63;
    float v = lrelu(__half2float(oh[idx]) * bnab[c] + bnab[64 + c]);
    hh[idx] = __float2half(v);
}

// ---------------- qmod/ext projection via MFMA (iteration 0 only) ----------
__global__ __launch_bounds__(256) void k_gemm(
    const __half* __restrict__ oh, const __half* __restrict__ hhin,
    const __half* __restrict__ wp, const float* __restrict__ bcomb,
    const float* __restrict__ bnab, int use_bn,
    __half* __restrict__ qh, float* __restrict__ ext, __half* __restrict__ hhout) {
    __shared__ __half qsm[64 * 68];
    int tid = threadIdx.x;
    int w = tid >> 6;
    int lane = tid & 63;
    int nloc = lane & 15;
    int kg = lane >> 4;
    int base = blockIdx.x * 64;

    half8_t A[2], AE[2];
    const half8_t* wpv = (const half8_t*)wp;
#pragma unroll
    for (int kh = 0; kh < 2; kh++) A[kh] = wpv[((w << 1) + kh) * 64 + lane];
    if (w == 3) {
#pragma unroll
        for (int kh = 0; kh < 2; kh++) AE[kh] = wpv[((8 << 1) + kh) * 64 + lane];
    }

    half8_t z8;
#pragma unroll
    for (int i = 0; i < 8; i++) z8[i] = (_Float16)0.f;

    half8_t B[4][2];
    int n[4];
    bool g[4];
#pragma unroll
    for (int nf = 0; nf < 4; nf++) {
        n[nf] = base + (nf << 4) + nloc;
        g[nf] = n[nf] < N_NODES;
    }

    if (use_bn) {
        float4 bnA[2][2], bnB[2][2];
#pragma unroll
        for (int kh = 0; kh < 2; kh++) {
            int k0 = (kh << 5) + (kg << 3);
            bnA[kh][0] = *(const float4*)&bnab[k0];
            bnA[kh][1] = *(const float4*)&bnab[k0 + 4];
            bnB[kh][0] = *(const float4*)&bnab[64 + k0];
            bnB[kh][1] = *(const float4*)&bnab[64 + k0 + 4];
        }
        const int4 zi4 = make_int4(0, 0, 0, 0);
#pragma unroll
        for (int nf = 0; nf < 4; nf++) {
            const __half* orow = oh + ((size_t)n[nf] << 6);
#pragma unroll
            for (int kh = 0; kh < 2; kh++) {
                int k0 = (kh << 5) + (kg << 3);
                int4 raw = g[nf] ? *(const int4*)&orow[k0] : zi4;
                const __half2* op = (const __half2*)&raw;
                float2 o01 = __half22float2(op[0]);
                float2 o23 = __half22float2(op[1]);
                float2 o45 = __half22float2(op[2]);
                float2 o67 = __half22float2(op[3]);
                float4 lo, hi;
                lo.x = lrelu(o01.x * bnA[kh][0].x + bnB[kh][0].x);
                lo.y = lrelu(o01.y * bnA[kh][0].y + bnB[kh][0].y);
                lo.z = lrelu(o23.x * bnA[kh][0].z + bnB[kh][0].z);
                lo.w = lrelu(o23.y * bnA[kh][0].w + bnB[kh][0].w);
                hi.x = lrelu(o45.x * bnA[kh][1].x + bnB[kh][1].x);
                hi.y = lrelu(o45.y * bnA[kh][1].y + bnB[kh][1].y);
                hi.z = lrelu(o67.x * bnA[kh][1].z + bnB[kh][1].z);
                hi.w = lrelu(o67.y * bnA[kh][1].w + bnB[kh][1].w);
                half8_t r;
                r[0] = (_Float16)lo.x; r[1] = (_Float16)lo.y;
                r[2] = (_Float16)lo.z; r[3] = (_Float16)lo.w;
                r[4] = (_Float16)hi.x; r[5] = (_Float16)hi.y;
                r[6] = (_Float16)hi.z; r[7] = (_Float16)hi.w;
                B[nf][kh] = r;
                if (g[nf]) *(half8_t*)&hhout[((size_t)n[nf] << 6) + k0] = r;
            }
        }
    } else {
#pragma unroll
        for (int nf = 0; nf < 4; nf++) {
#pragma unroll
            for (int kh = 0; kh < 2; kh++) {
                int k0 = (kh << 5) + (kg << 3);
                B[nf][kh] = g[nf] ? *(const half8_t*)&hhin[((size_t)n[nf] << 6) + k0]
                                  : z8;
            }
        }
    }

    f32x4 acc[4], accE[4];
#pragma unroll
    for (int nf = 0; nf < 4; nf++) {
        acc[nf] = (f32x4){0.f, 0.f, 0.f, 0.f};
        accE[nf] = (f32x4){0.f, 0.f, 0.f, 0.f};
    }

#pragma unroll
    for (int nf = 0; nf < 4; nf++) {
        acc[nf] = __builtin_amdgcn_mfma_f32_16x16x32_f16(A[0], B[nf][0], acc[nf],
                                                          0, 0, 0);
        acc[nf] = __builtin_amdgcn_mfma_f32_16x16x32_f16(A[1], B[nf][1], acc[nf],
                                                          0, 0, 0);
    }
    if (w == 3) {
#pragma unroll
        for (int nf = 0; nf < 4; nf++) {
            accE[nf] = __builtin_amdgcn_mfma_f32_16x16x32_f16(AE[0], B[nf][0],
                                                              accE[nf], 0, 0, 0);
            accE[nf] = __builtin_amdgcn_mfma_f32_16x16x32_f16(AE[1], B[nf][1],
                                                              accE[nf], 0, 0, 0);
        }
    }

    int rowg = kg << 2;
    int c0 = (w << 4) + rowg;
    float4 bi = *(const float4*)&bcomb[c0];
#pragma unroll
    for (int nf = 0; nf < 4; nf++) {
        int nl = (nf << 4) + nloc;
        __half2 p0 = __floats2half2_rn(acc[nf][0] + bi.x, acc[nf][1] + bi.y);
        __half2 p1 = __floats2half2_rn(acc[nf][2] + bi.z, acc[nf][3] + bi.w);
        *(__half2*)&qsm[nl * 68 + c0] = p0;
        *(__half2*)&qsm[nl * 68 + c0 + 2] = p1;
    }
    if (w == 3 && kg == 0) {
        float4 be = *(const float4*)&bcomb[128];
#pragma unroll
        for (int nf = 0; nf < 4; nf++) {
            if (!g[nf]) continue;
            float4 r;
            r.x = accE[nf][0] + be.x;
            r.y = accE[nf][1] + be.y;
            r.z = accE[nf][2] + be.z;
            r.w = accE[nf][3] + be.w;
            *(float4*)&ext[(size_t)n[nf] << 2] = r;
        }
    }
    __syncthreads();
#pragma unroll
    for (int rep = 0; rep < 8; rep++) {
        int i = rep * 256 + tid;
        int row = i >> 5;
        int col = (i & 31) << 1;
        if (base + row < N_NODES) {
            int v = *(int*)&qsm[row * 68 + col];
            *(int*)&qh[((size_t)(base + row) << 6) + col] = v;
        }
    }
}

// ---------------- fused iteration: aggH + proj + (next-gemm | MLP) ----------------
// Round-7 post-mortem: __launch_bounds__(256,8) capped VGPR at 64 -> accv[16]
// spilled to scratch (WRITE +270MB, FETCH +96MB = 1.6M edges x 16 floats x r+w);
// dur 94.8 -> 134us. Occupancy must come from the LDS cut (30.7 -> 19.5KB),
// never from squeezing VGPRs below the accumulator's need. Plain bounds here:
// round-6 showed the compiler picks ~52 VGPR naturally, which already permits
// 8 blocks/CU at this LDS footprint. Butterfly reduction retained (bank
// conflicts 3.4M -> 0.2-0.6M).
template <int LAST>
__global__ __launch_bounds__(256) void k_fused(
    __half* qh, float* ext,                     // in-place: own rows read then written
    const __half* __restrict__ hh_in, __half* __restrict__ hh_out,
    const int* __restrict__ idx, const int2* __restrict__ csr,
    const __half* __restrict__ wp, const __half* __restrict__ wvp,
    const float* __restrict__ We, const float* __restrict__ bv,
    const float* __restrict__ bcomb,
    const float* __restrict__ Wf1, const float* __restrict__ bf1,
    const float* __restrict__ Wf2, const float* __restrict__ bf2v,
    const float* __restrict__ mask, float* __restrict__ out,
    int bucket) {
    constexpr int RSM_BYTES = LAST ? (64 * 68 * 4) : (64 * 72 * 2);
    __shared__ __align__(16) char smem[RSM_BYTES + 9216 + 1024];
    __half* rsm16 = (__half*)smem;                // phase 2/3a: r f16 [64][72]
    float* rsm32 = (float*)smem;                  // phase 2/3b: r f32 [64][68]
    __half* Shatsm = (__half*)(smem + RSM_BYTES); // phase 1/2: [64][72] f16
    __half* qsm = (__half*)(smem + RSM_BYTES);    // phase 3a reuse
    float* W1sm = (float*)(smem + RSM_BYTES);     // phase 3b reuse [64][32]
    float4* svecsm = (float4*)(smem + RSM_BYTES + 9216);  // [64]

    int tid = threadIdx.x;
    int wv = tid >> 6;
    int lane = tid & 63;
    int base = blockIdx.x * 64;

    // ---- phase 1: aggregation; wave wv owns nodes base+wv*16 .. +15 ----
    {
        int es = lane >> 2, cl = lane & 3;
        // final channel after butterfly: cl*16 + bitrev4(es)
        int jf = ((es & 1) << 3) | ((es & 2) << 1) | ((es & 4) >> 1) | ((es & 8) >> 3);
        int shatcol = (cl << 4) + jf;
        for (int nl = 0; nl < 16; nl++) {
            int node = base + (wv << 4) + nl;
            if (node >= N_NODES) continue;   // wave-uniform
            float4 ex = *(const float4*)&ext[(size_t)node << 2];
            float beta = ex.x, qe0 = ex.y, qe1 = ex.z;
            int4 qr0 = *(const int4*)&qh[((size_t)node << 6) + (cl << 4)];
            int4 qr1 = *(const int4*)&qh[((size_t)node << 6) + (cl << 4) + 8];
            const half2_t* qp0 = (const half2_t*)&qr0;
            const half2_t* qp1 = (const half2_t*)&qr1;

            float l = 0.f, sA = 0.f, sB = 0.f;
            float accv[16];
#pragma unroll
            for (int c = 0; c < 16; c++) accv[c] = 0.f;

            int nEdge, rbase2;
            if (bucket) {
                nEdge = idx[node];
                rbase2 = node << 6;
            } else {
                rbase2 = idx[node];
                nEdge = idx[node + 1] - rbase2;
            }
            int nIter = (nEdge + 15) >> 4;

            auto body = [&](int4 h0, int4 h1, int2 rec, bool ok) {
                const half2_t* hp0 = (const half2_t*)&h0;
                const half2_t* hp1 = (const half2_t*)&h1;
                float t = 0.f;
#if __has_builtin(__builtin_amdgcn_fdot2)
#pragma unroll
                for (int p = 0; p < 4; p++)
                    t = __builtin_amdgcn_fdot2(hp0[p], qp0[p], t, false);
#pragma unroll
                for (int p = 0; p < 4; p++)
                    t = __builtin_amdgcn_fdot2(hp1[p], qp1[p], t, false);
#else
                const __half* hq0 = (const __half*)&qr0;
                const __half* hq1 = (const __half*)&qr1;
                const __half* hh0 = (const __half*)&h0;
                const __half* hh1 = (const __half*)&h1;
#pragma unroll
                for (int c = 0; c < 8; c++)
                    t += __half2float(hh0[c]) * __half2float(hq0[c]);
#pragma unroll
                for (int c = 0; c < 8; c++)
                    t += __half2float(hh1[c]) * __half2float(hq1[c]);
#endif
                t += __shfl_xor(t, 1, 64);
                t += __shfl_xor(t, 2, 64);
                float2 ef = __half22float2(*(__half2*)&rec.y);
                t += beta + ef.x * qe0 + ef.y * qe1;
                float pp = ok ? __expf(t) : 0.f;
                l += pp;
                sA += pp * ef.x;
                sB += pp * ef.y;
                const __half* hs0 = (const __half*)&h0;
                const __half* hs1 = (const __half*)&h1;
#pragma unroll
                for (int c = 0; c < 8; c++) accv[c] += pp * __half2float(hs0[c]);
#pragma unroll
                for (int c = 0; c < 8; c++) accv[8 + c] += pp * __half2float(hs1[c]);
            };

            if (bucket) {
                int2 recs[4];
#pragma unroll
                for (int i = 0; i < 4; i++) {
                    int e = (i << 4) + es;
                    recs[i] = (e < nEdge) ? csr[(size_t)rbase2 + e] : make_int2(0, 0);
                }
                if (nIter > 0) {
                    int src0 = recs[0].x & 0xFFFFF;
                    const __half* hr = hh_in + ((size_t)src0 << 6) + (cl << 4);
                    int4 h0c = *(const int4*)&hr[0];
                    int4 h1c = *(const int4*)&hr[8];
#pragma unroll
                    for (int i = 0; i < 4; i++) {
                        if (i < nIter) {
                            int4 h0 = h0c, h1 = h1c;
                            if (i + 1 < nIter) {
                                int srcn = recs[i + 1].x & 0xFFFFF;
                                const __half* hrn =
                                    hh_in + ((size_t)srcn << 6) + (cl << 4);
                                h0c = *(const int4*)&hrn[0];
                                h1c = *(const int4*)&hrn[8];
                            }
                            body(h0, h1, recs[i], ((i << 4) + es) < nEdge);
                        }
                    }
                }
            } else {
                for (int i = 0; i < nIter; i++) {
                    int e = (i << 4) + es;
                    bool ok = e < nEdge;
                    int2 rec = ok ? csr[(size_t)rbase2 + e] : make_int2(0, 0);
                    int src = rec.x & 0xFFFFF;
                    const __half* hr = hh_in + ((size_t)src << 6) + (cl << 4);
                    int4 h0 = *(const int4*)&hr[0];
                    int4 h1 = *(const int4*)&hr[8];
                    body(h0, h1, rec, ok);
                }
            }

#pragma unroll
            for (int D = 4; D < 64; D <<= 1) {
                l += __shfl_xor(l, D, 64);
                sA += __shfl_xor(sA, D, 64);
                sB += __shfl_xor(sB, D, 64);
            }
            float inv = 1.f / (l + 1e-16f);

            // register butterfly over edge-slot lane bits: keep-half exchange.
#pragma unroll
            for (int step = 0; step < 4; step++) {
                int m = 4 << step;
                int half = 8 >> step;
                bool up = (lane & m) != 0;
#pragma unroll
                for (int i = 0; i < half; i++) {
                    float send = up ? accv[i] : accv[i + half];
                    float recv = __shfl_xor(send, m, 64);
                    float keep = up ? accv[i + half] : accv[i];
                    accv[i] = keep + recv;
                }
            }
            // 64 lanes -> 64 distinct channels: 2 halves/bank, conflict-free
            Shatsm[((wv << 4) + nl) * 72 + shatcol] = __float2half(accv[0] * inv);
            if (lane == 0)
                svecsm[(wv << 4) + nl] = make_float4(sA * inv, sB * inv, l * inv, 0.f);
        }
    }
    __syncthreads();   // Shatsm/svecsm complete; ext/qh fully read

    // ---- phase 2: proj -> r (into rsm) ----
    {
        int nloc = lane & 15, kg = lane >> 4;
        const half8_t* wvv = (const half8_t*)wvp;
        const half8_t* wpv = (const half8_t*)wp;
        half8_t Av0 = wvv[((wv << 1) + 0) * 64 + lane];
        half8_t Av1 = wvv[((wv << 1) + 1) * 64 + lane];
        half8_t As0 = wpv[(((4 + wv) << 1) + 0) * 64 + lane];
        half8_t As1 = wpv[(((4 + wv) << 1) + 1) * 64 + lane];

        int rowg = kg << 2;
        int c0 = (wv << 4) + rowg;
        float4 we0 = *(const float4*)&We[c0];
        float4 we1 = *(const float4*)&We[64 + c0];
        float4 bv4 = *(const float4*)&bv[c0];
        float4 bs4 = *(const float4*)&bcomb[64 + c0];

        half8_t z8;
#pragma unroll
        for (int i = 0; i < 8; i++) z8[i] = (_Float16)0.f;

#pragma unroll
        for (int nf = 0; nf < 4; nf++) {
            int n = base + (nf << 4) + nloc;
            bool g = n < N_NODES;
            int nl2 = (nf << 4) + nloc;
            const __half* srow = &Shatsm[nl2 * 72];
            const __half* hrow = hh_in + ((size_t)n << 6);
            half8_t Bs0 = g ? *(const half8_t*)&srow[kg << 3] : z8;
            half8_t Bs1 = g ? *(const half8_t*)&srow[32 + (kg << 3)] : z8;
            half8_t Bh0 = g ? *(const half8_t*)&hrow[kg << 3] : z8;
            half8_t Bh1 = g ? *(const half8_t*)&hrow[32 + (kg << 3)] : z8;

            f32x4 acc = (f32x4){0.f, 0.f, 0.f, 0.f};
            acc = __builtin_amdgcn_mfma_f32_16x16x32_f16(Av0, Bs0, acc, 0, 0, 0);
            acc = __builtin_amdgcn_mfma_f32_16x16x32_f16(Av1, Bs1, acc, 0, 0, 0);
            acc = __builtin_amdgcn_mfma_f32_16x16x32_f16(As0, Bh0, acc, 0, 0, 0);
            acc = __builtin_amdgcn_mfma_f32_16x16x32_f16(As1, Bh1, acc, 0, 0, 0);

            float4 sv = g ? svecsm[nl2] : make_float4(0.f, 0.f, 0.f, 0.f);
            float4 r;
            r.x = lrelu(acc[0] + sv.x * we0.x + sv.y * we1.x + sv.z * bv4.x + bs4.x);
            r.y = lrelu(acc[1] + sv.x * we0.y + sv.y * we1.y + sv.z * bv4.y + bs4.y);
            r.z = lrelu(acc[2] + sv.x * we0.z + sv.y * we1.z + sv.z * bv4.z + bs4.z);
            r.w = lrelu(acc[3] + sv.x * we0.w + sv.y * we1.w + sv.z * bv4.w + bs4.w);

            if (LAST) {
                *(float4*)&rsm32[nl2 * 68 + c0] = r;
            } else {
                __half2 p0 = __floats2half2_rn(r.x, r.y);
                __half2 p1 = __floats2half2_rn(r.z, r.w);
                *(__half2*)&rsm16[nl2 * 72 + c0] = p0;
                *(__half2*)&rsm16[nl2 * 72 + c0 + 2] = p1;
            }
        }
    }
    __syncthreads();   // rsm complete; Shatsm region free

    if (!LAST) {
        // ---- phase 3a: next iteration's qmod/ext from r ----
        int nloc = lane & 15, kg = lane >> 4;
        const half8_t* wpv = (const half8_t*)wp;
        half8_t A0 = wpv[((wv << 1) + 0) * 64 + lane];
        half8_t A1 = wpv[((wv << 1) + 1) * 64 + lane];
        half8_t AE0 = A0, AE1 = A1;
        if (wv == 3) {
            AE0 = wpv[16 * 64 + lane];
            AE1 = wpv[17 * 64 + lane];
        }
        int rowg = kg << 2;
        int c0 = (wv << 4) + rowg;
        float4 bi = *(const float4*)&bcomb[c0];

#pragma unroll
        for (int nf = 0; nf < 4; nf++) {
            int nl2 = (nf << 4) + nloc;
            const __half* rrow = &rsm16[nl2 * 72];
            half8_t B0 = *(const half8_t*)&rrow[kg << 3];
            half8_t B1 = *(const half8_t*)&rrow[32 + (kg << 3)];
            f32x4 acc = (f32x4){0.f, 0.f, 0.f, 0.f};
            acc = __builtin_amdgcn_mfma_f32_16x16x32_f16(A0, B0, acc, 0, 0, 0);
            acc = __builtin_amdgcn_mfma_f32_16x16x32_f16(A1, B1, acc, 0, 0, 0);
            __half2 p0 = __floats2half2_rn(acc[0] + bi.x, acc[1] + bi.y);
            __half2 p1 = __floats2half2_rn(acc[2] + bi.z, acc[3] + bi.w);
            *(__half2*)&qsm[nl2 * 72 + c0] = p0;
            *(__half2*)&qsm[nl2 * 72 + c0 + 2] = p1;
            if (wv == 3) {
                f32x4 ae = (f32x4){0.f, 0.f, 0.f, 0.f};
                ae = __builtin_amdgcn_mfma_f32_16x16x32_f16(AE0, B0, ae, 0, 0, 0);
                ae = __builtin_amdgcn_mfma_f32_16x16x32_f16(AE1, B1, ae, 0, 0, 0);
                if (kg == 0) {
                    int n = base + nl2;
                    if (n < N_NODES) {
                        float4 be = *(const float4*)&bcomb[128];
                        float4 r;
                        r.x = ae[0] + be.x;
                        r.y = ae[1] + be.y;
                        r.z = ae[2] + be.z;
                        r.w = ae[3] + be.w;
                        *(float4*)&ext[(size_t)n << 2] = r;
                    }
                }
            }
        }
        __syncthreads();
        // coalesced row writes: qh (from qsm) + hh_out (from rsm16)
#pragma unroll
        for (int rep = 0; rep < 8; rep++) {
            int i = rep * 256 + tid;
            int row = i >> 5;
            int col = (i & 31) << 1;
            if (base + row < N_NODES) {
                *(int*)&qh[((size_t)(base + row) << 6) + col] =
                    *(int*)&qsm[row * 72 + col];
                *(int*)&hh_out[((size_t)(base + row) << 6) + col] =
                    *(int*)&rsm16[row * 72 + col];
            }
        }
    } else {
        // ---- phase 3b: fused MLP 64->32->1, * mask ----
        for (int i = tid; i < 2048; i += 256) W1sm[i] = Wf1[i];
        __syncthreads();
        int nl2 = tid >> 2, jg = tid & 3;
        int node = base + nl2;
        float a8[8];
        const float* b1p = &bf1[jg << 3];
#pragma unroll
        for (int k = 0; k < 8; k++) a8[k] = b1p[k];
        const float* hr = &rsm32[nl2 * 68];
        for (int c = 0; c < 64; c++) {
            float hv = hr[c];
            const float* wr = &W1sm[(c << 5) + (jg << 3)];
            float4 wa = *(const float4*)&wr[0];
            float4 wb = *(const float4*)&wr[4];
            a8[0] += hv * wa.x; a8[1] += hv * wa.y;
            a8[2] += hv * wa.z; a8[3] += hv * wa.w;
            a8[4] += hv * wb.x; a8[5] += hv * wb.y;
            a8[6] += hv * wb.z; a8[7] += hv * wb.w;
        }
        const float* w2p = &Wf2[jg << 3];
        float zs = 0.f;
#pragma unroll
        for (int k = 0; k < 8; k++) zs += lrelu(a8[k]) * w2p[k];
        zs += __shfl_xor(zs, 1, 64);
        zs += __shfl_xor(zs, 2, 64);
        if (jg == 0 && node < N_NODES)
            out[node] = (zs + bf2v[0]) * mask[node];
    }
}

extern "C" void kernel_launch(void* const* d_in, const int* in_sizes, int n_in,
                              void* d_out, int out_size, void* d_ws, size_t ws_size,
                              hipStream_t stream) {
    const float* x = (const float*)d_in[0];
    const int* ei = (const int*)d_in[1];
    const float* ea = (const float*)d_in[2];
    const float* mask = (const float*)d_in[3];
    const float *Wq1 = (const float*)d_in[4], *bq1 = (const float*)d_in[5];
    const float *Wk1 = (const float*)d_in[6], *bk1 = (const float*)d_in[7];
    const float *Wv1 = (const float*)d_in[8], *bv1 = (const float*)d_in[9];
    const float *We1 = (const float*)d_in[10];
    const float *Ws1 = (const float*)d_in[11], *bs1 = (const float*)d_in[12];
    const float *Wq2 = (const float*)d_in[13], *bq2 = (const float*)d_in[14];
    const float *Wk2 = (const float*)d_in[15], *bk2 = (const float*)d_in[16];
    const float *Wv2 = (const float*)d_in[17], *bv2 = (const float*)d_in[18];
    const float *We2 = (const float*)d_in[19];
    const float *Ws2 = (const float*)d_in[20], *bs2 = (const float*)d_in[21];
    const float *gamma = (const float*)d_in[22], *beta = (const float*)d_in[23];
    const float *Wf1 = (const float*)d_in[24], *bf1 = (const float*)d_in[25];
    const float *Wf2 = (const float*)d_in[26], *bf2v = (const float*)d_in[27];
    float* out = (float*)d_out;

    const size_t bucket_need =
        (size_t)NB_BKT * BCAP * 8 + (size_t)N_NODES * 64 * 8 +
        (size_t)N_NODES * 64 * 2 * 4 +   // qh, oh, hh0, hh1 (f16)
        (size_t)N_NODES * 16 +           // ext
        (size_t)N_NODES * 4 * 3 + (1 << 20);
    bool use_bucket = ws_size >= bucket_need;

    char* ws = (char*)d_ws;
    size_t off = 0;
    auto alloc = [&](size_t b) {
        size_t r = off;
        off += (b + 255) & ~(size_t)255;
        return r;
    };
    int* deg = (int*)(ws + alloc(N_NODES * 4));
    int* fill = (int*)(ws + alloc(N_NODES * 4));
    int* rowptr = (int*)(ws + alloc((N_NODES + 1) * 4));
    int* bsum = (int*)(ws + alloc(SCAN_B * 4));
    int* gCur = (int*)(ws + alloc(NB_BKT * 4));
    float* bnsum = (float*)(ws + alloc(64 * 4));
    float* bnsq = (float*)(ws + alloc(64 * 4));
    float* bnab = (float*)(ws + alloc(128 * 4));
    float* Wcomb = (float*)(ws + alloc(9216 * 4));
    float* bcomb = (float*)(ws + alloc(160 * 4));
    __half* wp = (__half*)(ws + alloc(9216 * 2));
    __half* wvp = (__half*)(ws + alloc(4096 * 2));
    float* ext = (float*)(ws + alloc((size_t)N_NODES * 16));
    int2* bin1 = (int2*)(ws + alloc(use_bucket ? (size_t)NB_BKT * BCAP * 8 : 256));
    int2* csr = (int2*)(ws + alloc(use_bucket ? (size_t)N_NODES * 64 * 8
                                              : (size_t)N_EDGES * 8));
    __half* qh = (__half*)(ws + alloc((size_t)N_NODES * 64 * 2));
    __half* oh = (__half*)(ws + alloc((size_t)N_NODES * 64 * 2));
    __half* hh0 = (__half*)(ws + alloc((size_t)N_NODES * 64 * 2));
    __half* hh1 = (__half*)(ws + alloc((size_t)N_NODES * 64 * 2));

    const int* srcI = ei;
    const int* tgtI = ei + N_EDGES;

    hipMemsetAsync(bnsum, 0, 64 * 4, stream);
    hipMemsetAsync(bnsq, 0, 64 * 4, stream);

    k_prep2<<<36, 256, 0, stream>>>(Wq2, Wk2, Ws2, We2, bk2, Wcomb);
    k_prepb<<<1, 192, 0, stream>>>(Wk2, We2, bq2, bk2, bs2, Wq1, Wk1, We1, bq1, bk1,
                                   bcomb);
    k_prepw<<<36, 256, 0, stream>>>(Wcomb, wp);
    k_prepv<<<16, 256, 0, stream>>>(Wv2, wvp);

    const int* aggIdx;
    if (use_bucket) {
        hipMemsetAsync(gCur, 0, NB_BKT * 4, stream);
        k_bin1<<<250, 256, 0, stream>>>(srcI, tgtI, (const float2*)ea, gCur, bin1);
        k_bin2<<<NB_BKT, 256, 0, stream>>>(gCur, bin1, csr, fill);
        aggIdx = fill;
    } else {
        hipMemsetAsync(deg, 0, N_NODES * 4, stream);
        k_count<<<N_EDGES / 256, 256, 0, stream>>>(tgtI, deg);
        k_scan1<<<SCAN_B, 256, 0, stream>>>(deg, bsum);
        k_scan2<<<1, 64, 0, stream>>>(bsum, rowptr);
        k_scan3<<<SCAN_B, 256, 0, stream>>>(deg, bsum, rowptr, fill);
        k_scatter<<<N_EDGES / 256, 256, 0, stream>>>(srcI, tgtI, (const float2*)ea,
                                                     fill, csr);
        aggIdx = rowptr;
    }
    int bkt = use_bucket ? 1 : 0;

    k_agg1<<<N_NODES / 4, 256, 0, stream>>>(x, aggIdx, csr, Wv1, We1, Ws1, bv1, bs1,
                                            bcomb + 144, oh, bkt);
    k_bnp<<<250, 256, 0, stream>>>(oh, bnsum, bnsq);
    k_bnf<<<1, 64, 0, stream>>>(bnsum, bnsq, gamma, beta, bnab);
    if (!use_bucket)
        k_bna<<<N_NODES * 64 / 256, 256, 0, stream>>>(oh, bnab, hh0);

    const int gemm_grid = (N_NODES + 63) / 64;
    // g0: qmod/ext for iteration 1; writes hh0 = h_a (BN'd h) in bucket path
    k_gemm<<<gemm_grid, 256, 0, stream>>>(oh, hh0, wp, bcomb, bnab, bkt, qh, ext,
                                          hh0);
    // F0/F1: aggregate+proj+next-gemm; F2: aggregate+proj+MLP -> out
    k_fused<0><<<gemm_grid, 256, 0, stream>>>(qh, ext, hh0, hh1, aggIdx, csr, wp,
                                              wvp, We2, bv2, bcomb, Wf1, bf1, Wf2,
                                              bf2v, mask, out, bkt);
    k_fused<0><<<gemm_grid, 256, 0, stream>>>(qh, ext, hh1, hh0, aggIdx, csr, wp,
                                              wvp, We2, bv2, bcomb, Wf1, bf1, Wf2,
                                              bf2v, mask, out, bkt);
    k_fused<1><<<gemm_grid, 256, 0, stream>>>(qh, ext, hh0, hh1, aggIdx, csr, wp,
                                              wvp, We2, bv2, bcomb, Wf1, bf1, Wf2,
                                              bf2v, mask, out, bkt);
}

// Round 9
// 504.946 us; speedup vs baseline: 1.2129x; 1.0533x over previous
//
#include <hip/hip_runtime.h>
#include <hip/hip_fp16.h>

#define N_NODES 100000
#define N_EDGES 1600000
#define SCAN_B ((N_NODES + 1023) / 1024)
#define BSHIFT 7
#define NB_BKT ((N_NODES + 127) / 128)   // 782
#define BCAP 2560                        // mean 2048, +11 sigma

typedef _Float16 half2_t __attribute__((ext_vector_type(2)));
typedef _Float16 half8_t __attribute__((ext_vector_type(8)));
typedef float f32x4 __attribute__((ext_vector_type(4)));

__device__ __forceinline__ float lrelu(float x) { return x >= 0.f ? x : 0.01f * x; }

// ---------------- dense CSR build (fallback when ws is small) ----------------
__global__ void k_count(const int* __restrict__ tgt, int* __restrict__ deg) {
    int i = blockIdx.x * 256 + threadIdx.x;
    atomicAdd(&deg[tgt[i]], 1);
}

__global__ void k_scan1(const int* __restrict__ deg, int* __restrict__ bsum) {
    __shared__ int s[256];
    int t = threadIdx.x;
    int gi = blockIdx.x * 1024 + t * 4;
    int v = 0;
    if (gi < N_NODES) {
        int4 d = *(const int4*)&deg[gi];
        v = d.x + d.y + d.z + d.w;
    }
    s[t] = v;
    __syncthreads();
    for (int d = 128; d > 0; d >>= 1) {
        if (t < d) s[t] += s[t + d];
        __syncthreads();
    }
    if (t == 0) bsum[blockIdx.x] = s[0];
}

__global__ void k_scan2(int* bsum, int* rowptr) {
    if (threadIdx.x == 0) {
        int run = 0;
        for (int b = 0; b < SCAN_B; b++) {
            int v = bsum[b];
            bsum[b] = run;
            run += v;
        }
        rowptr[N_NODES] = run;
    }
}

__global__ void k_scan3(const int* __restrict__ deg, const int* __restrict__ bsum,
                        int* __restrict__ rowptr, int* __restrict__ fill) {
    __shared__ int s[256];
    int t = threadIdx.x;
    int gi = blockIdx.x * 1024 + t * 4;
    int4 d = make_int4(0, 0, 0, 0);
    if (gi < N_NODES) d = *(const int4*)&deg[gi];
    int tsum = d.x + d.y + d.z + d.w;
    s[t] = tsum;
    __syncthreads();
    for (int dd = 1; dd < 256; dd <<= 1) {
        int val = (t >= dd) ? s[t - dd] : 0;
        __syncthreads();
        s[t] += val;
        __syncthreads();
    }
    int texcl = s[t] - tsum + bsum[blockIdx.x];
    if (gi < N_NODES) {
        int4 w;
        w.x = texcl;
        w.y = texcl + d.x;
        w.z = texcl + d.x + d.y;
        w.w = texcl + d.x + d.y + d.z;
        *(int4*)&rowptr[gi] = w;
        *(int4*)&fill[gi] = w;
    }
}

__global__ void k_scatter(const int* __restrict__ src, const int* __restrict__ tgt,
                          const float2* __restrict__ ea,
                          int* __restrict__ fill, int2* __restrict__ csr) {
    int i = blockIdx.x * 256 + threadIdx.x;
    int t = tgt[i];
    float2 e = ea[i];
    int pos = atomicAdd(&fill[t], 1);
    __half2 h2 = __floats2half2_rn(e.x, e.y);
    csr[pos] = make_int2(src[i], *(int*)&h2);
}

// ---------------- two-level binning (bucket path) ----------------
__global__ __launch_bounds__(256) void k_bin1(const int* __restrict__ src,
                                              const int* __restrict__ tgt,
                                              const float2* __restrict__ ea,
                                              int* __restrict__ gCur,
                                              int2* __restrict__ bin) {
    __shared__ int hist[NB_BKT];
    __shared__ int cur[NB_BKT];
    int tid = threadIdx.x;
    for (int b = tid; b < NB_BKT; b += 256) hist[b] = 0;
    __syncthreads();
    int base = blockIdx.x * 6400;
#pragma unroll 5
    for (int k = 0; k < 25; k++) {
        int i = base + k * 256 + tid;
        atomicAdd(&hist[tgt[i] >> BSHIFT], 1);
    }
    __syncthreads();
    for (int b = tid; b < NB_BKT; b += 256)
        cur[b] = atomicAdd(&gCur[b], hist[b]);
    __syncthreads();
    for (int k = 0; k < 25; k++) {
        int i = base + k * 256 + tid;
        int t = tgt[i];
        int b = t >> BSHIFT;
        float2 e = ea[i];
        int pos = atomicAdd(&cur[b], 1);
        if (pos < BCAP) {
            __half2 h2 = __floats2half2_rn(e.x, e.y);
            int2 rec;
            rec.x = src[i] | ((t & 127) << 20);
            rec.y = *(int*)&h2;
            bin[(size_t)b * BCAP + pos] = rec;
        }
    }
}

__global__ __launch_bounds__(256) void k_bin2(const int* __restrict__ gCnt,
                                              const int2* __restrict__ bin,
                                              int2* __restrict__ csr,
                                              int* __restrict__ fill) {
    __shared__ int cnt[128];
    int tid = threadIdx.x;
    if (tid < 128) cnt[tid] = 0;
    __syncthreads();
    int b = blockIdx.x;
    int nb = min(gCnt[b], BCAP);
    const int2* myb = &bin[(size_t)b * BCAP];
    for (int i = tid; i < nb; i += 256) {
        int2 rec = myb[i];
        int tloc = (rec.x >> 20) & 127;
        int s = rec.x & 0xFFFFF;
        int pos = atomicAdd(&cnt[tloc], 1);
        if (pos < 64) {
            int node = (b << BSHIFT) + tloc;
            csr[((size_t)node << 6) + pos] = make_int2(s | (rec.x & 0xFFF00000), rec.y);
        }
    }
    __syncthreads();
    if (tid < 128) {
        int node = (b << BSHIFT) + tid;
        if (node < N_NODES) fill[node] = min(cnt[tid], 64);
    }
}

// ---------------- weight precompute ----------------
// Wcomb[64 k][144 c]: c 0-63 qmod (=0.125*Wq2 Wk2^T), 64-127 Ws2, 128 beta (u2),
// 129-130 qe (G), 131-143 zero.
__global__ void k_prep2(const float* __restrict__ Wq, const float* __restrict__ Wk,
                        const float* __restrict__ Ws, const float* __restrict__ We,
                        const float* __restrict__ bk, float* __restrict__ Wcomb) {
    int idx = blockIdx.x * 256 + threadIdx.x;  // 0..9215
    if (idx >= 9216) return;
    int j = idx / 144;
    int m = idx - j * 144;
    float v = 0.f;
    if (m < 64) {
        float s = 0.f;
        for (int ch = 0; ch < 64; ch++) s += Wq[j * 64 + ch] * Wk[m * 64 + ch];
        v = 0.125f * s;
    } else if (m < 128) {
        v = Ws[j * 64 + (m - 64)];
    } else if (m == 128) {
        float s = 0.f;
        for (int ch = 0; ch < 64; ch++) s += Wq[j * 64 + ch] * bk[ch];
        v = 0.125f * s;
    } else if (m <= 130) {
        float s = 0.f;
        for (int ch = 0; ch < 64; ch++) s += Wq[j * 64 + ch] * We[(m - 129) * 64 + ch];
        v = 0.125f * s;
    }
    Wcomb[idx] = v;
}

// bcomb[0..143]: biases for the 144 output channels; bcomb[144..159]: layer-1 consts
__global__ void k_prepb(const float* __restrict__ Wk2, const float* __restrict__ We2,
                        const float* __restrict__ bq2, const float* __restrict__ bk2,
                        const float* __restrict__ bs2, const float* __restrict__ Wq1,
                        const float* __restrict__ Wk1, const float* __restrict__ We1,
                        const float* __restrict__ bq1, const float* __restrict__ bk1,
                        float* __restrict__ bcomb) {
    int t = threadIdx.x;
    if (t >= 160) return;
    float v = 0.f;
    if (t < 64) {
        float s = 0.f;
        for (int i = 0; i < 64; i++) s += Wk2[t * 64 + i] * bq2[i];
        v = 0.125f * s;
    } else if (t < 128) {
        v = bs2[t - 64];
    } else if (t == 128) {
        float s = 0.f;
        for (int i = 0; i < 64; i++) s += bq2[i] * bk2[i];
        v = 0.125f * s;
    } else if (t <= 130) {
        float s = 0.f;
        for (int i = 0; i < 64; i++) s += bq2[i] * We2[(t - 129) * 64 + i];
        v = 0.125f * s;
    } else if (t < 144) {
        v = 0.f;
    } else {
        int t2 = t - 144;
        float s = 0.f;
        if (t2 < 4) {            // A1[j][m], j=t2>>1, m=t2&1
            int j = t2 >> 1, m = t2 & 1;
            for (int ch = 0; ch < 64; ch++) s += Wq1[j * 64 + ch] * Wk1[m * 64 + ch];
        } else if (t2 < 6) {     // u1[j]
            int j = t2 - 4;
            for (int ch = 0; ch < 64; ch++) s += Wq1[j * 64 + ch] * bk1[ch];
        } else if (t2 < 8) {     // w1[m]
            int m = t2 - 6;
            for (int ch = 0; ch < 64; ch++) s += bq1[ch] * Wk1[m * 64 + ch];
        } else if (t2 == 8) {    // c1
            for (int ch = 0; ch < 64; ch++) s += bq1[ch] * bk1[ch];
        } else if (t2 < 13) {    // B1[j][d]
            int j = (t2 - 9) >> 1, d = (t2 - 9) & 1;
            for (int ch = 0; ch < 64; ch++) s += Wq1[j * 64 + ch] * We1[d * 64 + ch];
        } else if (t2 < 15) {    // d1[d]
            int d = t2 - 13;
            for (int ch = 0; ch < 64; ch++) s += bq1[ch] * We1[d * 64 + ch];
        }
        v = 0.125f * s;
    }
    bcomb[t] = v;
}

// pack Wcomb into MFMA A-fragments: 9 M-frags x 2 kh x 64 lanes x 8 elems
__global__ void k_prepw(const float* __restrict__ Wcomb, __half* __restrict__ wp) {
    int t = blockIdx.x * 256 + threadIdx.x;  // 0..9215
    if (t >= 9216) return;
    int e = t & 7;
    int lane = (t >> 3) & 63;
    int kh = (t >> 9) & 1;
    int fm = t >> 10;  // 0..8
    int k = (kh << 5) + ((lane >> 4) << 3) + e;
    int c = fm * 16 + (lane & 15);
    wp[t] = __float2half(Wcomb[k * 144 + c]);
}

// pack Wv2 into MFMA A-fragments: 4 M-frags x 2 kh x 64 lanes x 8 elems
__global__ void k_prepv(const float* __restrict__ Wv, __half* __restrict__ wvp) {
    int t = blockIdx.x * 256 + threadIdx.x;  // 0..4095
    if (t >= 4096) return;
    int e = t & 7;
    int lane = (t >> 3) & 63;
    int kh = (t >> 9) & 1;
    int fm = t >> 10;  // 0..3
    int k = (kh << 5) + ((lane >> 4) << 3) + e;
    int c = fm * 16 + (lane & 15);
    wvp[t] = __float2half(Wv[k * 64 + c]);
}

// ---------------- layer 1 aggregation (2-dim trick) + fused BN partial stats ----
// Round-8 change: bnp folded in; per-block channel sums go to a 32-way-split
// accumulator (25K blocks -> ~780 atomics per address, no TCC serialization).
__global__ __launch_bounds__(256) void k_agg1(
    const float* __restrict__ x, const int* __restrict__ idx,
    const int2* __restrict__ csr, const float* __restrict__ Wv,
    const float* __restrict__ We, const float* __restrict__ Ws,
    const float* __restrict__ bv, const float* __restrict__ bs,
    const float* __restrict__ prep, __half* __restrict__ oh,
    float* __restrict__ bnsum, float* __restrict__ bnsq, int bucket) {
    __shared__ float s1[256], s2[256];
    int tid = threadIdx.x;
    int node = blockIdx.x * 4 + (tid >> 6);
    int lane = tid & 63;
    float2 xt = *(const float2*)&x[(size_t)node << 1];
    float a0 = xt.x * prep[0] + xt.y * prep[2] + prep[6];
    float a1 = xt.x * prep[1] + xt.y * prep[3] + prep[7];
    float b1 = xt.x * prep[4] + xt.y * prep[5] + prep[8];
    float g0 = xt.x * prep[9] + xt.y * prep[11] + prep[13];
    float g1 = xt.x * prep[10] + xt.y * prep[12] + prep[14];

    float l = 0.f, px0 = 0.f, px1 = 0.f, pA = 0.f, pB = 0.f;
    if (bucket) {
        int deg = idx[node];
        bool valid = lane < deg;
        int2 rec = valid ? csr[((size_t)node << 6) + lane] : make_int2(0, 0);
        int src = rec.x & 0xFFFFF;
        float2 ef = __half22float2(*(__half2*)&rec.y);
        float2 xs = valid ? *(const float2*)&x[(size_t)src << 1] : make_float2(0.f, 0.f);
        float t = a0 * xs.x + a1 * xs.y + b1 + g0 * ef.x + g1 * ef.y;
        float pp = valid ? __expf(t) : 0.f;
        l = pp;
        px0 = pp * xs.x;
        px1 = pp * xs.y;
        pA = pp * ef.x;
        pB = pp * ef.y;
    } else {
        int beg = idx[node], end = idx[node + 1];
        for (int p = beg + lane; p < end; p += 64) {
            int2 rec = csr[p];
            float2 ef = __half22float2(*(__half2*)&rec.y);
            float2 xs = *(const float2*)&x[(size_t)rec.x << 1];
            float t = a0 * xs.x + a1 * xs.y + b1 + g0 * ef.x + g1 * ef.y;
            float pp = __expf(t);
            l += pp;
            px0 += pp * xs.x;
            px1 += pp * xs.y;
            pA += pp * ef.x;
            pB += pp * ef.y;
        }
    }
#pragma unroll
    for (int D = 1; D < 64; D <<= 1) {
        l += __shfl_xor(l, D, 64);
        px0 += __shfl_xor(px0, D, 64);
        px1 += __shfl_xor(px1, D, 64);
        pA += __shfl_xor(pA, D, 64);
        pB += __shfl_xor(pB, D, 64);
    }
    float inv = 1.f / (l + 1e-16f);
    int c = lane;
    float r = (px0 * Wv[c] + px1 * Wv[64 + c] + pA * We[c] + pB * We[64 + c] +
               l * bv[c]) * inv +
              xt.x * Ws[c] + xt.y * Ws[64 + c] + bs[c];
    oh[((size_t)node << 6) + c] = __float2half(r);
    s1[tid] = r;
    s2[tid] = r * r;
    __syncthreads();
    if (tid < 64) {
        float a = s1[tid] + s1[tid + 64] + s1[tid + 128] + s1[tid + 192];
        float b = s2[tid] + s2[tid + 64] + s2[tid + 128] + s2[tid + 192];
        int slot = (blockIdx.x & 31) << 6;
        atomicAdd(&bnsum[slot + tid], a);
        atomicAdd(&bnsq[slot + tid], b);
    }
}

__global__ void k_bnf(const float* bnsum, const float* bnsq, const float* gamma,
                      const float* beta, float* bnab) {
    int c = threadIdx.x;
    float su = 0.f, sq = 0.f;
    for (int s = 0; s < 32; s++) {
        su += bnsum[(s << 6) + c];
        sq += bnsq[(s << 6) + c];
    }
    float mean = su * (1.f / N_NODES);
    float var = sq * (1.f / N_NODES) - mean * mean;
    float A = gamma[c] * rsqrtf(var + 1e-5f);
    bnab[c] = A;
    bnab[64 + c] = beta[c] - mean * A;
}

__global__ void k_bna(const __half* __restrict__ oh, const float* __restrict__ bnab,
                      __half* __restrict__ hh) {
    int idx = blockIdx.x * 256 + threadIdx.x;
    int c = idx & 63;
    float v = lrelu(__half2float(oh[idx]) * bnab[c] + bnab[64 + c]);
    hh[idx] = __float2half(v);
}

// ---------------- fused iteration: [phase0 qmod] + aggH + proj + (next-gemm | MLP) --
// Round-8 post-mortem: occupancy 5->8 blocks/CU gained ~0 (gather runs at its
// random-access fabric floor, dur == FETCH/1TB/s). Remaining lever is dispatch
// elimination: FIRST variant computes its own nodes' qmod/ext via MFMA into LDS
// (replacing the standalone k_gemm dispatch, ~50us); hh0 comes from k_bna.
template <int FIRST, int LAST>
__global__ __launch_bounds__(256) void k_fused(
    __half* qh, float* ext,                     // in-place: own rows read then written
    const __half* __restrict__ hh_in, __half* __restrict__ hh_out,
    const int* __restrict__ idx, const int2* __restrict__ csr,
    const __half* __restrict__ wp, const __half* __restrict__ wvp,
    const float* __restrict__ We, const float* __restrict__ bv,
    const float* __restrict__ bcomb,
    const float* __restrict__ Wf1, const float* __restrict__ bf1,
    const float* __restrict__ Wf2, const float* __restrict__ bf2v,
    const float* __restrict__ mask, float* __restrict__ out,
    int bucket) {
    constexpr int RSM_BYTES = LAST ? (64 * 68 * 4) : (64 * 72 * 2);
    constexpr int EXT_BYTES = FIRST ? 1024 : 0;
    __shared__ __align__(16) char smem[RSM_BYTES + 9216 + 1024 + EXT_BYTES];
    __half* rsm16 = (__half*)smem;                // phase 2/3a: r f16 [64][72]
    float* rsm32 = (float*)smem;                  // phase 2/3b: r f32 [64][68]
    __half* qsmA = (__half*)smem;                 // FIRST phase0/1: qmod [64][72]
    __half* Shatsm = (__half*)(smem + RSM_BYTES); // phase 1/2: [64][72] f16
    __half* qsm = (__half*)(smem + RSM_BYTES);    // phase 3a reuse
    float* W1sm = (float*)(smem + RSM_BYTES);     // phase 3b reuse [64][32]
    float4* svecsm = (float4*)(smem + RSM_BYTES + 9216);           // [64]
    float4* extsm = (float4*)(smem + RSM_BYTES + 9216 + 1024);     // [64] (FIRST)

    int tid = threadIdx.x;
    int wv = tid >> 6;
    int lane = tid & 63;
    int base = blockIdx.x * 64;

    // ---- phase 0 (FIRST): qmod/ext for own 64 nodes from hh_in, into LDS ----
    if (FIRST) {
        int nloc = lane & 15, kg = lane >> 4;
        const half8_t* wpv = (const half8_t*)wp;
        half8_t A0 = wpv[((wv << 1) + 0) * 64 + lane];
        half8_t A1 = wpv[((wv << 1) + 1) * 64 + lane];
        half8_t AE0 = A0, AE1 = A1;
        if (wv == 3) {
            AE0 = wpv[16 * 64 + lane];
            AE1 = wpv[17 * 64 + lane];
        }
        int rowg = kg << 2;
        int c0 = (wv << 4) + rowg;
        float4 bi = *(const float4*)&bcomb[c0];
        half8_t z8;
#pragma unroll
        for (int i = 0; i < 8; i++) z8[i] = (_Float16)0.f;
#pragma unroll
        for (int nf = 0; nf < 4; nf++) {
            int n = base + (nf << 4) + nloc;
            bool g = n < N_NODES;
            int nl2 = (nf << 4) + nloc;
            const __half* hrow = hh_in + ((size_t)n << 6);
            half8_t B0 = g ? *(const half8_t*)&hrow[kg << 3] : z8;
            half8_t B1 = g ? *(const half8_t*)&hrow[32 + (kg << 3)] : z8;
            f32x4 acc = (f32x4){0.f, 0.f, 0.f, 0.f};
            acc = __builtin_amdgcn_mfma_f32_16x16x32_f16(A0, B0, acc, 0, 0, 0);
            acc = __builtin_amdgcn_mfma_f32_16x16x32_f16(A1, B1, acc, 0, 0, 0);
            __half2 p0 = __floats2half2_rn(acc[0] + bi.x, acc[1] + bi.y);
            __half2 p1 = __floats2half2_rn(acc[2] + bi.z, acc[3] + bi.w);
            *(__half2*)&qsmA[nl2 * 72 + c0] = p0;
            *(__half2*)&qsmA[nl2 * 72 + c0 + 2] = p1;
            if (wv == 3) {
                f32x4 ae = (f32x4){0.f, 0.f, 0.f, 0.f};
                ae = __builtin_amdgcn_mfma_f32_16x16x32_f16(AE0, B0, ae, 0, 0, 0);
                ae = __builtin_amdgcn_mfma_f32_16x16x32_f16(AE1, B1, ae, 0, 0, 0);
                if (kg == 0 && g) {
                    float4 be = *(const float4*)&bcomb[128];
                    extsm[nl2] = make_float4(ae[0] + be.x, ae[1] + be.y,
                                             ae[2] + be.z, ae[3] + be.w);
                }
            }
        }
        __syncthreads();
    }

    // ---- phase 1: aggregation; wave wv owns nodes base+wv*16 .. +15 ----
    {
        int es = lane >> 2, cl = lane & 3;
        // final channel after butterfly: cl*16 + bitrev4(es)
        int jf = ((es & 1) << 3) | ((es & 2) << 1) | ((es & 4) >> 1) | ((es & 8) >> 3);
        int shatcol = (cl << 4) + jf;
        for (int nl = 0; nl < 16; nl++) {
            int node = base + (wv << 4) + nl;
            if (node >= N_NODES) continue;   // wave-uniform
            float4 ex;
            int4 qr0, qr1;
            if (FIRST) {
                ex = extsm[(wv << 4) + nl];
                qr0 = *(const int4*)&qsmA[((wv << 4) + nl) * 72 + (cl << 4)];
                qr1 = *(const int4*)&qsmA[((wv << 4) + nl) * 72 + (cl << 4) + 8];
            } else {
                ex = *(const float4*)&ext[(size_t)node << 2];
                qr0 = *(const int4*)&qh[((size_t)node << 6) + (cl << 4)];
                qr1 = *(const int4*)&qh[((size_t)node << 6) + (cl << 4) + 8];
            }
            float beta = ex.x, qe0 = ex.y, qe1 = ex.z;
            const half2_t* qp0 = (const half2_t*)&qr0;
            const half2_t* qp1 = (const half2_t*)&qr1;

            float l = 0.f, sA = 0.f, sB = 0.f;
            float accv[16];
#pragma unroll
            for (int c = 0; c < 16; c++) accv[c] = 0.f;

            int nEdge, rbase2;
            if (bucket) {
                nEdge = idx[node];
                rbase2 = node << 6;
            } else {
                rbase2 = idx[node];
                nEdge = idx[node + 1] - rbase2;
            }
            int nIter = (nEdge + 15) >> 4;

            auto body = [&](int4 h0, int4 h1, int2 rec, bool ok) {
                const half2_t* hp0 = (const half2_t*)&h0;
                const half2_t* hp1 = (const half2_t*)&h1;
                float t = 0.f;
#if __has_builtin(__builtin_amdgcn_fdot2)
#pragma unroll
                for (int p = 0; p < 4; p++)
                    t = __builtin_amdgcn_fdot2(hp0[p], qp0[p], t, false);
#pragma unroll
                for (int p = 0; p < 4; p++)
                    t = __builtin_amdgcn_fdot2(hp1[p], qp1[p], t, false);
#else
                const __half* hq0 = (const __half*)&qr0;
                const __half* hq1 = (const __half*)&qr1;
                const __half* hh0 = (const __half*)&h0;
                const __half* hh1 = (const __half*)&h1;
#pragma unroll
                for (int c = 0; c < 8; c++)
                    t += __half2float(hh0[c]) * __half2float(hq0[c]);
#pragma unroll
                for (int c = 0; c < 8; c++)
                    t += __half2float(hh1[c]) * __half2float(hq1[c]);
#endif
                t += __shfl_xor(t, 1, 64);
                t += __shfl_xor(t, 2, 64);
                float2 ef = __half22float2(*(__half2*)&rec.y);
                t += beta + ef.x * qe0 + ef.y * qe1;
                float pp = ok ? __expf(t) : 0.f;
                l += pp;
                sA += pp * ef.x;
                sB += pp * ef.y;
                const __half* hs0 = (const __half*)&h0;
                const __half* hs1 = (const __half*)&h1;
#pragma unroll
                for (int c = 0; c < 8; c++) accv[c] += pp * __half2float(hs0[c]);
#pragma unroll
                for (int c = 0; c < 8; c++) accv[8 + c] += pp * __half2float(hs1[c]);
            };

            if (bucket) {
                int2 recs[4];
#pragma unroll
                for (int i = 0; i < 4; i++) {
                    int e = (i << 4) + es;
                    recs[i] = (e < nEdge) ? csr[(size_t)rbase2 + e] : make_int2(0, 0);
                }
                if (nIter > 0) {
                    int src0 = recs[0].x & 0xFFFFF;
                    const __half* hr = hh_in + ((size_t)src0 << 6) + (cl << 4);
                    int4 h0c = *(const int4*)&hr[0];
                    int4 h1c = *(const int4*)&hr[8];
#pragma unroll
                    for (int i = 0; i < 4; i++) {
                        if (i < nIter) {
                            int4 h0 = h0c, h1 = h1c;
                            if (i + 1 < nIter) {
                                int srcn = recs[i + 1].x & 0xFFFFF;
                                const __half* hrn =
                                    hh_in + ((size_t)srcn << 6) + (cl << 4);
                                h0c = *(const int4*)&hrn[0];
                                h1c = *(const int4*)&hrn[8];
                            }
                            body(h0, h1, recs[i], ((i << 4) + es) < nEdge);
                        }
                    }
                }
            } else {
                for (int i = 0; i < nIter; i++) {
                    int e = (i << 4) + es;
                    bool ok = e < nEdge;
                    int2 rec = ok ? csr[(size_t)rbase2 + e] : make_int2(0, 0);
                    int src = rec.x & 0xFFFFF;
                    const __half* hr = hh_in + ((size_t)src << 6) + (cl << 4);
                    int4 h0 = *(const int4*)&hr[0];
                    int4 h1 = *(const int4*)&hr[8];
                    body(h0, h1, rec, ok);
                }
            }

#pragma unroll
            for (int D = 4; D < 64; D <<= 1) {
                l += __shfl_xor(l, D, 64);
                sA += __shfl_xor(sA, D, 64);
                sB += __shfl_xor(sB, D, 64);
            }
            float inv = 1.f / (l + 1e-16f);

            // register butterfly over edge-slot lane bits: keep-half exchange.
#pragma unroll
            for (int step = 0; step < 4; step++) {
                int m = 4 << step;
                int half = 8 >> step;
                bool up = (lane & m) != 0;
#pragma unroll
                for (int i = 0; i < half; i++) {
                    float send = up ? accv[i] : accv[i + half];
                    float recv = __shfl_xor(send, m, 64);
                    float keep = up ? accv[i + half] : accv[i];
                    accv[i] = keep + recv;
                }
            }
            // 64 lanes -> 64 distinct channels: 2 halves/bank, conflict-free
            Shatsm[((wv << 4) + nl) * 72 + shatcol] = __float2half(accv[0] * inv);
            if (lane == 0)
                svecsm[(wv << 4) + nl] = make_float4(sA * inv, sB * inv, l * inv, 0.f);
        }
    }
    __syncthreads();   // Shatsm/svecsm complete; qsmA dead; ext/qh fully read

    // ---- phase 2: proj -> r (into rsm) ----
    {
        int nloc = lane & 15, kg = lane >> 4;
        const half8_t* wvv = (const half8_t*)wvp;
        const half8_t* wpv = (const half8_t*)wp;
        half8_t Av0 = wvv[((wv << 1) + 0) * 64 + lane];
        half8_t Av1 = wvv[((wv << 1) + 1) * 64 + lane];
        half8_t As0 = wpv[(((4 + wv) << 1) + 0) * 64 + lane];
        half8_t As1 = wpv[(((4 + wv) << 1) + 1) * 64 + lane];

        int rowg = kg << 2;
        int c0 = (wv << 4) + rowg;
        float4 we0 = *(const float4*)&We[c0];
        float4 we1 = *(const float4*)&We[64 + c0];
        float4 bv4 = *(const float4*)&bv[c0];
        float4 bs4 = *(const float4*)&bcomb[64 + c0];

        half8_t z8;
#pragma unroll
        for (int i = 0; i < 8; i++) z8[i] = (_Float16)0.f;

#pragma unroll
        for (int nf = 0; nf < 4; nf++) {
            int n = base + (nf << 4) + nloc;
            bool g = n < N_NODES;
            int nl2 = (nf << 4) + nloc;
            const __half* srow = &Shatsm[nl2 * 72];
            const __half* hrow = hh_in + ((size_t)n << 6);
            half8_t Bs0 = g ? *(const half8_t*)&srow[kg << 3] : z8;
            half8_t Bs1 = g ? *(const half8_t*)&srow[32 + (kg << 3)] : z8;
            half8_t Bh0 = g ? *(const half8_t*)&hrow[kg << 3] : z8;
            half8_t Bh1 = g ? *(const half8_t*)&hrow[32 + (kg << 3)] : z8;

            f32x4 acc = (f32x4){0.f, 0.f, 0.f, 0.f};
            acc = __builtin_amdgcn_mfma_f32_16x16x32_f16(Av0, Bs0, acc, 0, 0, 0);
            acc = __builtin_amdgcn_mfma_f32_16x16x32_f16(Av1, Bs1, acc, 0, 0, 0);
            acc = __builtin_amdgcn_mfma_f32_16x16x32_f16(As0, Bh0, acc, 0, 0, 0);
            acc = __builtin_amdgcn_mfma_f32_16x16x32_f16(As1, Bh1, acc, 0, 0, 0);

            float4 sv = g ? svecsm[nl2] : make_float4(0.f, 0.f, 0.f, 0.f);
            float4 r;
            r.x = lrelu(acc[0] + sv.x * we0.x + sv.y * we1.x + sv.z * bv4.x + bs4.x);
            r.y = lrelu(acc[1] + sv.x * we0.y + sv.y * we1.y + sv.z * bv4.y + bs4.y);
            r.z = lrelu(acc[2] + sv.x * we0.z + sv.y * we1.z + sv.z * bv4.z + bs4.z);
            r.w = lrelu(acc[3] + sv.x * we0.w + sv.y * we1.w + sv.z * bv4.w + bs4.w);

            if (LAST) {
                *(float4*)&rsm32[nl2 * 68 + c0] = r;
            } else {
                __half2 p0 = __floats2half2_rn(r.x, r.y);
                __half2 p1 = __floats2half2_rn(r.z, r.w);
                *(__half2*)&rsm16[nl2 * 72 + c0] = p0;
                *(__half2*)&rsm16[nl2 * 72 + c0 + 2] = p1;
            }
        }
    }
    __syncthreads();   // rsm complete; Shatsm region free

    if (!LAST) {
        // ---- phase 3a: next iteration's qmod/ext from r ----
        int nloc = lane & 15, kg = lane >> 4;
        const half8_t* wpv = (const half8_t*)wp;
        half8_t A0 = wpv[((wv << 1) + 0) * 64 + lane];
        half8_t A1 = wpv[((wv << 1) + 1) * 64 + lane];
        half8_t AE0 = A0, AE1 = A1;
        if (wv == 3) {
            AE0 = wpv[16 * 64 + lane];
            AE1 = wpv[17 * 64 + lane];
        }
        int rowg = kg << 2;
        int c0 = (wv << 4) + rowg;
        float4 bi = *(const float4*)&bcomb[c0];

#pragma unroll
        for (int nf = 0; nf < 4; nf++) {
            int nl2 = (nf << 4) + nloc;
            const __half* rrow = &rsm16[nl2 * 72];
            half8_t B0 = *(const half8_t*)&rrow[kg << 3];
            half8_t B1 = *(const half8_t*)&rrow[32 + (kg << 3)];
            f32x4 acc = (f32x4){0.f, 0.f, 0.f, 0.f};
            acc = __builtin_amdgcn_mfma_f32_16x16x32_f16(A0, B0, acc, 0, 0, 0);
            acc = __builtin_amdgcn_mfma_f32_16x16x32_f16(A1, B1, acc, 0, 0, 0);
            __half2 p0 = __floats2half2_rn(acc[0] + bi.x, acc[1] + bi.y);
            __half2 p1 = __floats2half2_rn(acc[2] + bi.z, acc[3] + bi.w);
            *(__half2*)&qsm[nl2 * 72 + c0] = p0;
            *(__half2*)&qsm[nl2 * 72 + c0 + 2] = p1;
            if (wv == 3) {
                f32x4 ae = (f32x4){0.f, 0.f, 0.f, 0.f};
                ae = __builtin_amdgcn_mfma_f32_16x16x32_f16(AE0, B0, ae, 0, 0, 0);
                ae = __builtin_amdgcn_mfma_f32_16x16x32_f16(AE1, B1, ae, 0, 0, 0);
                if (kg == 0) {
                    int n = base + nl2;
                    if (n < N_NODES) {
                        float4 be = *(const float4*)&bcomb[128];
                        float4 r;
                        r.x = ae[0] + be.x;
                        r.y = ae[1] + be.y;
                        r.z = ae[2] + be.z;
                        r.w = ae[3] + be.w;
                        *(float4*)&ext[(size_t)n << 2] = r;
                    }
                }
            }
        }
        __syncthreads();
        // coalesced row writes: qh (from qsm) + hh_out (from rsm16)
#pragma unroll
        for (int rep = 0; rep < 8; rep++) {
            int i = rep * 256 + tid;
            int row = i >> 5;
            int col = (i & 31) << 1;
            if (base + row < N_NODES) {
                *(int*)&qh[((size_t)(base + row) << 6) + col] =
                    *(int*)&qsm[row * 72 + col];
                *(int*)&hh_out[((size_t)(base + row) << 6) + col] =
                    *(int*)&rsm16[row * 72 + col];
            }
        }
    } else {
        // ---- phase 3b: fused MLP 64->32->1, * mask ----
        for (int i = tid; i < 2048; i += 256) W1sm[i] = Wf1[i];
        __syncthreads();
        int nl2 = tid >> 2, jg = tid & 3;
        int node = base + nl2;
        float a8[8];
        const float* b1p = &bf1[jg << 3];
#pragma unroll
        for (int k = 0; k < 8; k++) a8[k] = b1p[k];
        const float* hr = &rsm32[nl2 * 68];
        for (int c = 0; c < 64; c++) {
            float hv = hr[c];
            const float* wr = &W1sm[(c << 5) + (jg << 3)];
            float4 wa = *(const float4*)&wr[0];
            float4 wb = *(const float4*)&wr[4];
            a8[0] += hv * wa.x; a8[1] += hv * wa.y;
            a8[2] += hv * wa.z; a8[3] += hv * wa.w;
            a8[4] += hv * wb.x; a8[5] += hv * wb.y;
            a8[6] += hv * wb.z; a8[7] += hv * wb.w;
        }
        const float* w2p = &Wf2[jg << 3];
        float zs = 0.f;
#pragma unroll
        for (int k = 0; k < 8; k++) zs += lrelu(a8[k]) * w2p[k];
        zs += __shfl_xor(zs, 1, 64);
        zs += __shfl_xor(zs, 2, 64);
        if (jg == 0 && node < N_NODES)
            out[node] = (zs + bf2v[0]) * mask[node];
    }
}

extern "C" void kernel_launch(void* const* d_in, const int* in_sizes, int n_in,
                              void* d_out, int out_size, void* d_ws, size_t ws_size,
                              hipStream_t stream) {
    const float* x = (const float*)d_in[0];
    const int* ei = (const int*)d_in[1];
    const float* ea = (const float*)d_in[2];
    const float* mask = (const float*)d_in[3];
    const float *Wq1 = (const float*)d_in[4], *bq1 = (const float*)d_in[5];
    const float *Wk1 = (const float*)d_in[6], *bk1 = (const float*)d_in[7];
    const float *Wv1 = (const float*)d_in[8], *bv1 = (const float*)d_in[9];
    const float *We1 = (const float*)d_in[10];
    const float *Ws1 = (const float*)d_in[11], *bs1 = (const float*)d_in[12];
    const float *Wq2 = (const float*)d_in[13], *bq2 = (const float*)d_in[14];
    const float *Wk2 = (const float*)d_in[15], *bk2 = (const float*)d_in[16];
    const float *Wv2 = (const float*)d_in[17], *bv2 = (const float*)d_in[18];
    const float *We2 = (const float*)d_in[19];
    const float *Ws2 = (const float*)d_in[20], *bs2 = (const float*)d_in[21];
    const float *gamma = (const float*)d_in[22], *beta = (const float*)d_in[23];
    const float *Wf1 = (const float*)d_in[24], *bf1 = (const float*)d_in[25];
    const float *Wf2 = (const float*)d_in[26], *bf2v = (const float*)d_in[27];
    float* out = (float*)d_out;

    const size_t bucket_need =
        (size_t)NB_BKT * BCAP * 8 + (size_t)N_NODES * 64 * 8 +
        (size_t)N_NODES * 64 * 2 * 4 +   // qh, oh, hh0, hh1 (f16)
        (size_t)N_NODES * 16 +           // ext
        (size_t)N_NODES * 4 * 3 + (1 << 20);
    bool use_bucket = ws_size >= bucket_need;

    char* ws = (char*)d_ws;
    size_t off = 0;
    auto alloc = [&](size_t b) {
        size_t r = off;
        off += (b + 255) & ~(size_t)255;
        return r;
    };
    int* deg = (int*)(ws + alloc(N_NODES * 4));
    int* fill = (int*)(ws + alloc(N_NODES * 4));
    int* rowptr = (int*)(ws + alloc((N_NODES + 1) * 4));
    int* bsum = (int*)(ws + alloc(SCAN_B * 4));
    int* gCur = (int*)(ws + alloc(NB_BKT * 4));
    float* bnsum = (float*)(ws + alloc(32 * 64 * 4));
    float* bnsq = (float*)(ws + alloc(32 * 64 * 4));
    float* bnab = (float*)(ws + alloc(128 * 4));
    float* Wcomb = (float*)(ws + alloc(9216 * 4));
    float* bcomb = (float*)(ws + alloc(160 * 4));
    __half* wp = (__half*)(ws + alloc(9216 * 2));
    __half* wvp = (__half*)(ws + alloc(4096 * 2));
    float* ext = (float*)(ws + alloc((size_t)N_NODES * 16));
    int2* bin1 = (int2*)(ws + alloc(use_bucket ? (size_t)NB_BKT * BCAP * 8 : 256));
    int2* csr = (int2*)(ws + alloc(use_bucket ? (size_t)N_NODES * 64 * 8
                                              : (size_t)N_EDGES * 8));
    __half* qh = (__half*)(ws + alloc((size_t)N_NODES * 64 * 2));
    __half* oh = (__half*)(ws + alloc((size_t)N_NODES * 64 * 2));
    __half* hh0 = (__half*)(ws + alloc((size_t)N_NODES * 64 * 2));
    __half* hh1 = (__half*)(ws + alloc((size_t)N_NODES * 64 * 2));

    const int* srcI = ei;
    const int* tgtI = ei + N_EDGES;

    hipMemsetAsync(bnsum, 0, 32 * 64 * 4, stream);
    hipMemsetAsync(bnsq, 0, 32 * 64 * 4, stream);

    k_prep2<<<36, 256, 0, stream>>>(Wq2, Wk2, Ws2, We2, bk2, Wcomb);
    k_prepb<<<1, 192, 0, stream>>>(Wk2, We2, bq2, bk2, bs2, Wq1, Wk1, We1, bq1, bk1,
                                   bcomb);
    k_prepw<<<36, 256, 0, stream>>>(Wcomb, wp);
    k_prepv<<<16, 256, 0, stream>>>(Wv2, wvp);

    const int* aggIdx;
    if (use_bucket) {
        hipMemsetAsync(gCur, 0, NB_BKT * 4, stream);
        k_bin1<<<250, 256, 0, stream>>>(srcI, tgtI, (const float2*)ea, gCur, bin1);
        k_bin2<<<NB_BKT, 256, 0, stream>>>(gCur, bin1, csr, fill);
        aggIdx = fill;
    } else {
        hipMemsetAsync(deg, 0, N_NODES * 4, stream);
        k_count<<<N_EDGES / 256, 256, 0, stream>>>(tgtI, deg);
        k_scan1<<<SCAN_B, 256, 0, stream>>>(deg, bsum);
        k_scan2<<<1, 64, 0, stream>>>(bsum, rowptr);
        k_scan3<<<SCAN_B, 256, 0, stream>>>(deg, bsum, rowptr, fill);
        k_scatter<<<N_EDGES / 256, 256, 0, stream>>>(srcI, tgtI, (const float2*)ea,
                                                     fill, csr);
        aggIdx = rowptr;
    }
    int bkt = use_bucket ? 1 : 0;

    k_agg1<<<N_NODES / 4, 256, 0, stream>>>(x, aggIdx, csr, Wv1, We1, Ws1, bv1, bs1,
                                            bcomb + 144, oh, bnsum, bnsq, bkt);
    k_bnf<<<1, 64, 0, stream>>>(bnsum, bnsq, gamma, beta, bnab);
    k_bna<<<N_NODES * 64 / 256, 256, 0, stream>>>(oh, bnab, hh0);

    const int gemm_grid = (N_NODES + 63) / 64;
    // F0: phase0 computes qh/ext in LDS from hh0; F0/F1 write next qh/ext + hh;
    // F2 ends in the fused MLP -> out.
    k_fused<1, 0><<<gemm_grid, 256, 0, stream>>>(qh, ext, hh0, hh1, aggIdx, csr, wp,
                                                 wvp, We2, bv2, bcomb, Wf1, bf1, Wf2,
                                                 bf2v, mask, out, bkt);
    k_fused<0, 0><<<gemm_grid, 256, 0, stream>>>(qh, ext, hh1, hh0, aggIdx, csr, wp,
                                                 wvp, We2, bv2, bcomb, Wf1, bf1, Wf2,
                                                 bf2v, mask, out, bkt);
    k_fused<0, 1><<<gemm_grid, 256, 0, stream>>>(qh, ext, hh0, hh1, aggIdx, csr, wp,
                                                 wvp, We2, bv2, bcomb, Wf1, bf1, Wf2,
                                                 bf2v, mask, out, bkt);
}